// Round 2
// baseline (2525.968 us; speedup 1.0000x reference)
//
#include <hip/hip_runtime.h>

// Problem constants (B=4, T=S=1024, E=1024, CTX=768, H=16, DH=64)
#define NB 4
#define TT 1024
#define SS 1024
#define EE 1024
#define CCH 768
#define NH 16
#define DHH 64
#define EPSF 1e-5f
#define SCALE_INV (1.0f/256.0f)   // SCALE = 1024 // (16**0.5) = 256.0

// ---------------------------------------------------------------------------
// Weight standardization: w [O,I] f32 -> wn [O,I] f32, per-row (w-mu)*rsqrt(var+eps)
// one block (256 thr) per row
// ---------------------------------------------------------------------------
__global__ __launch_bounds__(256) void ws_norm_kernel(const float* __restrict__ w,
                                                      float* __restrict__ wn, int I) {
    int row = blockIdx.x;
    const float* wr = w + (size_t)row * I;
    float s = 0.f, s2 = 0.f;
    for (int i = threadIdx.x; i < I; i += 256) {
        float v = wr[i];
        s += v; s2 += v * v;
    }
#pragma unroll
    for (int off = 32; off > 0; off >>= 1) {
        s  += __shfl_down(s, off);
        s2 += __shfl_down(s2, off);
    }
    __shared__ float sa[4], sb[4];
    __shared__ float smean, srstd;
    int wid = threadIdx.x >> 6;
    if ((threadIdx.x & 63) == 0) { sa[wid] = s; sb[wid] = s2; }
    __syncthreads();
    if (threadIdx.x == 0) {
        float ts = sa[0] + sa[1] + sa[2] + sa[3];
        float ts2 = sb[0] + sb[1] + sb[2] + sb[3];
        float mean = ts / (float)I;
        float var = ts2 / (float)I - mean * mean;
        smean = mean;
        srstd = rsqrtf(var + EPSF);
    }
    __syncthreads();
    float mean = smean, r = srstd;
    float* wo = wn + (size_t)row * I;
    for (int i = threadIdx.x; i < I; i += 256) wo[i] = (wr[i] - mean) * r;
}

// ---------------------------------------------------------------------------
// Projection GEMM: C[b] = A [O,I] f32 @ B[b] [I,L] f32, + bias, mask over L,
// optional residual (added AFTER masking, per reference). 64x64 tile, 4x4/thread.
// grid: (L/64, O/64, NB), block 256
// ---------------------------------------------------------------------------
__global__ __launch_bounds__(256) void proj_gemm_kernel(
    const float* __restrict__ A, const float* __restrict__ Bm,
    const float* __restrict__ bias, const int* __restrict__ mask,
    const float* __restrict__ resid, float* __restrict__ C,
    int O, int I, int L) {
    int tid = threadIdx.x;
    int tx = tid & 15, ty = tid >> 4;
    int l0 = blockIdx.x * 64, o0 = blockIdx.y * 64, b = blockIdx.z;
    const float* Bp = Bm + (size_t)b * I * L;

    __shared__ float As[16][68];  // [k][o]
    __shared__ float Bs[16][68];  // [k][l]

    float acc[4][4] = {};
    for (int k0 = 0; k0 < I; k0 += 16) {
        __syncthreads();
#pragma unroll
        for (int m = 0; m < 4; m++) {
            int idx = tid + 256 * m;
            int r = idx >> 4, c = idx & 15;       // A tile 64 rows x 16 k
            As[c][r] = A[(size_t)(o0 + r) * I + (k0 + c)];
            int kr = idx >> 6, col = idx & 63;    // B tile 16 k x 64 l
            Bs[kr][col] = Bp[(size_t)(k0 + kr) * L + (l0 + col)];
        }
        __syncthreads();
#pragma unroll
        for (int kk = 0; kk < 16; kk++) {
            float4 a4 = *(const float4*)&As[kk][ty * 4];
            float4 b4 = *(const float4*)&Bs[kk][tx * 4];
            float av[4] = {a4.x, a4.y, a4.z, a4.w};
            float bv[4] = {b4.x, b4.y, b4.z, b4.w};
#pragma unroll
            for (int i = 0; i < 4; i++)
#pragma unroll
                for (int j = 0; j < 4; j++) acc[i][j] += av[i] * bv[j];
        }
    }
    const int* mrow = mask + (size_t)b * L;
#pragma unroll
    for (int i = 0; i < 4; i++) {
        int o = o0 + ty * 4 + i;
        float bi = bias[o];
        size_t rowoff = ((size_t)b * O + o) * L;
#pragma unroll
        for (int j = 0; j < 4; j++) {
            int l = l0 + tx * 4 + j;
            float v = mrow[l] ? (acc[i][j] + bi) : 0.f;
            if (resid) v += resid[rowoff + l];
            C[rowoff + l] = v;
        }
    }
}

// ---------------------------------------------------------------------------
// Per-head LayerNorm over DH (in place on f32 buffer [NB,EE,L]); one thread
// owns one (b,h,l) group of 64 strided elements -> in-place safe.
// ---------------------------------------------------------------------------
__global__ __launch_bounds__(256) void ln_heads_kernel(float* __restrict__ y,
                                                       const float* __restrict__ g,
                                                       const float* __restrict__ beta, int L) {
    int idx = blockIdx.x * 256 + threadIdx.x;  // NB*NH*L threads
    int l = idx % L;
    int bh = idx / L;
    int h = bh % NH, b = bh / NH;
    size_t base = ((size_t)(b * EE + h * DHH)) * L + l;
    float v[DHH];
    float s = 0.f;
#pragma unroll
    for (int d = 0; d < DHH; d++) { v[d] = y[base + (size_t)d * L]; s += v[d]; }
    float mean = s * (1.f / DHH);
    float s2 = 0.f;
#pragma unroll
    for (int d = 0; d < DHH; d++) { float dv = v[d] - mean; s2 += dv * dv; }
    float r = rsqrtf(s2 * (1.f / DHH) + EPSF);
#pragma unroll
    for (int d = 0; d < DHH; d++)
        y[base + (size_t)d * L] = (v[d] - mean) * r * g[d] + beta[d];
}

// ---------------------------------------------------------------------------
// Pass A: softmax row stats over T for each (b,h,s).
// sc[s,t] = (sum_d k[d,s] q[d,t]) / 256 ; masked t -> -1e9 ; online m/l.
// Block: (b,h, s-tile 64); loops t-tiles of 64; 4x4 register blocking.
// grid: (SS/64, NH, NB)
// ---------------------------------------------------------------------------
__global__ __launch_bounds__(256) void attn_stats_kernel(
    const float* __restrict__ qln, const float* __restrict__ kln,
    const int* __restrict__ mask, float* __restrict__ mrow, float* __restrict__ lrow) {
    int s0 = blockIdx.x * 64, h = blockIdx.y, b = blockIdx.z;
    int tid = threadIdx.x, tx = tid & 15, ty = tid >> 4;
    __shared__ float ks[64][64];  // [d][s]
    __shared__ float qs[64][64];  // [d][t]
    const size_t headK = ((size_t)(b * EE + h * DHH)) * SS;
    const size_t headQ = ((size_t)(b * EE + h * DHH)) * TT;
#pragma unroll
    for (int m = 0; m < 16; m++) {
        int idx = tid + 256 * m;
        int d = idx >> 6, s = idx & 63;
        ks[d][s] = kln[headK + (size_t)d * SS + s0 + s];
    }
    const int* mk = mask + (size_t)b * TT;
    float mi[4] = {-3e38f, -3e38f, -3e38f, -3e38f};
    float li[4] = {0.f, 0.f, 0.f, 0.f};
    for (int t0 = 0; t0 < TT; t0 += 64) {
        __syncthreads();
#pragma unroll
        for (int m = 0; m < 16; m++) {
            int idx = tid + 256 * m;
            int d = idx >> 6, t = idx & 63;
            qs[d][t] = qln[headQ + (size_t)d * TT + t0 + t];
        }
        __syncthreads();
        float acc[4][4] = {};
#pragma unroll
        for (int d = 0; d < 64; d++) {
            float4 k4 = *(const float4*)&ks[d][ty * 4];
            float4 q4 = *(const float4*)&qs[d][tx * 4];
            float kv[4] = {k4.x, k4.y, k4.z, k4.w};
            float qv[4] = {q4.x, q4.y, q4.z, q4.w};
#pragma unroll
            for (int i = 0; i < 4; i++)
#pragma unroll
                for (int j = 0; j < 4; j++) acc[i][j] += kv[i] * qv[j];
        }
#pragma unroll
        for (int i = 0; i < 4; i++) {
#pragma unroll
            for (int j = 0; j < 4; j++) {
                float sc = acc[i][j] * SCALE_INV;
                if (!mk[t0 + tx * 4 + j]) sc = -1e9f;
                float mn = fmaxf(mi[i], sc);
                li[i] = li[i] * __expf(mi[i] - mn) + __expf(sc - mn);
                mi[i] = mn;
            }
        }
    }
    // combine across the 16 tx lanes sharing each s row (consecutive lanes)
#pragma unroll
    for (int i = 0; i < 4; i++) {
        float m = mi[i], l = li[i];
#pragma unroll
        for (int off = 1; off < 16; off <<= 1) {
            float mo = __shfl_xor(m, off);
            float lo = __shfl_xor(l, off);
            float mn = fmaxf(m, mo);
            l = l * __expf(m - mn) + lo * __expf(mo - mn);
            m = mn;
        }
        if (tx == 0) {
            int s = s0 + ty * 4 + i;
            mrow[((size_t)(b * NH + h)) * SS + s] = m;
            lrow[((size_t)(b * NH + h)) * SS + s] = l;
        }
    }
}

// ---------------------------------------------------------------------------
// Pass B: out[b,h,d,t] = sum_s v[d,s] * P[s,t],
// P[s,t] = mask_ctx[s] ? exp(sc[s,t]-m_s)/l_s : 0 (sc masked over t like pass A).
// Block: (b,h, t-tile 64); loops s-tiles of 64. kv LDS buffer reused K->V.
// grid: (TT/64, NH, NB)
// ---------------------------------------------------------------------------
__global__ __launch_bounds__(256) void attn_pv_kernel(
    const float* __restrict__ qln, const float* __restrict__ kln, const float* __restrict__ vln,
    const int* __restrict__ mask, const int* __restrict__ mask_ctx,
    const float* __restrict__ mrow, const float* __restrict__ lrow,
    float* __restrict__ outb) {
    int t0 = blockIdx.x * 64, h = blockIdx.y, b = blockIdx.z;
    int tid = threadIdx.x, tx = tid & 15, ty = tid >> 4;
    __shared__ float qs[64][64];   // [d][t]
    __shared__ float kv[64][68];   // first used as k: [d][s]; then v: [s][d]
    __shared__ float ps[64][64];   // [s][t]
    const size_t headQ = ((size_t)(b * EE + h * DHH)) * TT;
    const size_t headK = ((size_t)(b * EE + h * DHH)) * SS;
#pragma unroll
    for (int m = 0; m < 16; m++) {
        int idx = tid + 256 * m;
        int d = idx >> 6, t = idx & 63;
        qs[d][t] = qln[headQ + (size_t)d * TT + t0 + t];
    }
    const int* mk = mask + (size_t)b * TT;
    const int* mc = mask_ctx + (size_t)b * SS;
    const float* mr = mrow + (size_t)(b * NH + h) * SS;
    const float* lr = lrow + (size_t)(b * NH + h) * SS;
    bool tmask[4];
#pragma unroll
    for (int j = 0; j < 4; j++) tmask[j] = (mk[t0 + tx * 4 + j] != 0);

    float out[4][4] = {};
    for (int s0 = 0; s0 < SS; s0 += 64) {
        __syncthreads();
#pragma unroll
        for (int m = 0; m < 16; m++) {   // K tile [d][s]
            int idx = tid + 256 * m;
            int d = idx >> 6, s = idx & 63;
            kv[d][s] = kln[headK + (size_t)d * SS + s0 + s];
        }
        __syncthreads();
        float acc[4][4] = {};
#pragma unroll
        for (int d = 0; d < 64; d++) {
            float4 k4 = *(const float4*)&kv[d][ty * 4];
            float4 q4 = *(const float4*)&qs[d][tx * 4];
            float kvv[4] = {k4.x, k4.y, k4.z, k4.w};
            float qv[4] = {q4.x, q4.y, q4.z, q4.w};
#pragma unroll
            for (int i = 0; i < 4; i++)
#pragma unroll
                for (int j = 0; j < 4; j++) acc[i][j] += kvv[i] * qv[j];
        }
        __syncthreads();
        // overwrite kv with V (transposed: [s][d]) + write P tile
#pragma unroll
        for (int m = 0; m < 16; m++) {
            int idx = tid + 256 * m;
            int d = idx >> 6, s = idx & 63;
            kv[s][d] = vln[headK + (size_t)d * SS + s0 + s];
        }
#pragma unroll
        for (int i = 0; i < 4; i++) {
            int s = s0 + ty * 4 + i;
            float m_s = mr[s];
            float rl = 1.f / lr[s];
            bool cm = (mc[s] != 0);
            float p[4];
#pragma unroll
            for (int j = 0; j < 4; j++) {
                float sc = tmask[j] ? acc[i][j] * SCALE_INV : -1e9f;
                p[j] = cm ? __expf(sc - m_s) * rl : 0.f;
            }
            *(float4*)&ps[ty * 4 + i][tx * 4] = make_float4(p[0], p[1], p[2], p[3]);
        }
        __syncthreads();
#pragma unroll
        for (int s = 0; s < 64; s++) {
            float4 v4 = *(const float4*)&kv[s][ty * 4];
            float4 p4 = *(const float4*)&ps[s][tx * 4];
            float vv[4] = {v4.x, v4.y, v4.z, v4.w};
            float pv[4] = {p4.x, p4.y, p4.z, p4.w};
#pragma unroll
            for (int i = 0; i < 4; i++)
#pragma unroll
                for (int j = 0; j < 4; j++) out[i][j] += vv[i] * pv[j];
        }
    }
#pragma unroll
    for (int i = 0; i < 4; i++) {
        size_t rowoff = ((size_t)(b * EE + h * DHH + ty * 4 + i)) * TT;
#pragma unroll
        for (int j = 0; j < 4; j++)
            outb[rowoff + t0 + tx * 4 + j] = out[i][j];
    }
}

// ---------------------------------------------------------------------------
extern "C" void kernel_launch(void* const* d_in, const int* in_sizes, int n_in,
                              void* d_out, int out_size, void* d_ws, size_t ws_size,
                              hipStream_t stream) {
    const float* x        = (const float*)d_in[0];
    const float* ctx      = (const float*)d_in[1];
    const int*   mask     = (const int*)d_in[2];
    const int*   mask_ctx = (const int*)d_in[3];
    const float* qw  = (const float*)d_in[4];
    const float* qbi = (const float*)d_in[5];
    const float* kw  = (const float*)d_in[6];
    const float* kbi = (const float*)d_in[7];
    const float* vw  = (const float*)d_in[8];
    const float* vbi = (const float*)d_in[9];
    const float* ow  = (const float*)d_in[10];
    const float* obi = (const float*)d_in[11];
    const float* gq = (const float*)d_in[12];
    const float* bq = (const float*)d_in[13];
    const float* gk = (const float*)d_in[14];
    const float* bk = (const float*)d_in[15];
    const float* gv = (const float*)d_in[16];
    const float* bv = (const float*)d_in[17];

    // workspace carve (~79 MB, all f32)
    float* wq_n = (float*)d_ws;                 // 1024*1024
    float* wk_n = wq_n + 1024 * 1024;           // 1024*768
    float* wv_n = wk_n + 1024 * CCH;            // 1024*768
    float* wo_n = wv_n + 1024 * CCH;            // 1024*1024
    float* q_s  = wo_n + 1024 * 1024;           // [NB,EE,TT]
    float* k_s  = q_s + (size_t)NB * EE * TT;   // [NB,EE,SS]
    float* v_s  = k_s + (size_t)NB * EE * SS;   // [NB,EE,SS]
    float* a_s  = v_s + (size_t)NB * EE * SS;   // attn out [NB,EE,TT]
    float* mrow = a_s + (size_t)NB * EE * TT;   // [NB*NH*SS]
    float* lrow = mrow + (size_t)NB * NH * SS;

    // 1) weight standardization
    ws_norm_kernel<<<1024, 256, 0, stream>>>(qw, wq_n, EE);
    ws_norm_kernel<<<1024, 256, 0, stream>>>(kw, wk_n, CCH);
    ws_norm_kernel<<<1024, 256, 0, stream>>>(vw, wv_n, CCH);
    ws_norm_kernel<<<1024, 256, 0, stream>>>(ow, wo_n, EE);

    // 2) q/k/v projections (+mask)
    proj_gemm_kernel<<<dim3(TT / 64, EE / 64, NB), 256, 0, stream>>>(
        wq_n, x, qbi, mask, nullptr, q_s, EE, EE, TT);
    proj_gemm_kernel<<<dim3(SS / 64, EE / 64, NB), 256, 0, stream>>>(
        wk_n, ctx, kbi, mask_ctx, nullptr, k_s, EE, CCH, SS);
    proj_gemm_kernel<<<dim3(SS / 64, EE / 64, NB), 256, 0, stream>>>(
        wv_n, ctx, vbi, mask_ctx, nullptr, v_s, EE, CCH, SS);

    // 3) per-head layernorm over DH (in place)
    ln_heads_kernel<<<(NB * NH * TT) / 256, 256, 0, stream>>>(q_s, gq, bq, TT);
    ln_heads_kernel<<<(NB * NH * SS) / 256, 256, 0, stream>>>(k_s, gk, bk, SS);
    ln_heads_kernel<<<(NB * NH * SS) / 256, 256, 0, stream>>>(v_s, gv, bv, SS);

    // 4) attention: stats pass then PV pass (softmax over T, contract over S)
    attn_stats_kernel<<<dim3(SS / 64, NH, NB), 256, 0, stream>>>(q_s, k_s, mask, mrow, lrow);
    attn_pv_kernel<<<dim3(TT / 64, NH, NB), 256, 0, stream>>>(q_s, k_s, v_s, mask, mask_ctx,
                                                              mrow, lrow, a_s);

    // 5) output projection + mask + residual -> d_out (f32)
    proj_gemm_kernel<<<dim3(TT / 64, EE / 64, NB), 256, 0, stream>>>(
        wo_n, a_s, obi, mask, x, (float*)d_out, EE, EE, TT);
}

// Round 3
// 379.654 us; speedup vs baseline: 6.6534x; 6.6534x over previous
//
#include <hip/hip_runtime.h>

// Problem constants (B=4, T=S=1024, E=1024, CTX=768, H=16, DH=64)
#define NB 4
#define TT 1024
#define SS 1024
#define EE 1024
#define CCH 768
#define NH 16
#define DHH 64
#define EPSF 1e-5f
#define SCALE_INV (1.0f/256.0f)   // SCALE = 1024 // (16**0.5) = 256.0

typedef unsigned short u16;
typedef __attribute__((ext_vector_type(8))) short short8;       // MFMA A/B frag (8 bf16)
typedef __attribute__((ext_vector_type(8))) unsigned short u16x8;
typedef __attribute__((ext_vector_type(4))) float f32x4;        // MFMA C/D frag

__device__ __forceinline__ u16 f2bu(float f) {
    union { float f; unsigned u; } x; x.f = f;
    unsigned r = x.u + 0x7fffu + ((x.u >> 16) & 1u);
    return (u16)(r >> 16);
}
__device__ __forceinline__ float bu2f(u16 u) {
    union { unsigned u; float f; } x; x.u = ((unsigned)u) << 16; return x.f;
}

#define MFMA16(a, b, c) __builtin_amdgcn_mfma_f32_16x16x32_bf16((a), (b), (c), 0, 0, 0)

// ---------------------------------------------------------------------------
// Weight standardization: w [O,I] f32 -> wn [O,I] bf16. One block per row.
// ---------------------------------------------------------------------------
__global__ __launch_bounds__(256) void ws_norm_kernel(const float* __restrict__ w,
                                                      u16* __restrict__ wn, int I) {
    int row = blockIdx.x;
    const float* wr = w + (size_t)row * I;
    float s = 0.f, s2 = 0.f;
    for (int i = threadIdx.x; i < I; i += 256) { float v = wr[i]; s += v; s2 += v * v; }
#pragma unroll
    for (int off = 32; off > 0; off >>= 1) { s += __shfl_down(s, off); s2 += __shfl_down(s2, off); }
    __shared__ float sa[4], sb[4], smean, srstd;
    int wid = threadIdx.x >> 6;
    if ((threadIdx.x & 63) == 0) { sa[wid] = s; sb[wid] = s2; }
    __syncthreads();
    if (threadIdx.x == 0) {
        float ts = sa[0] + sa[1] + sa[2] + sa[3];
        float ts2 = sb[0] + sb[1] + sb[2] + sb[3];
        float mean = ts / (float)I;
        float var = ts2 / (float)I - mean * mean;
        smean = mean; srstd = rsqrtf(var + EPSF);
    }
    __syncthreads();
    float mean = smean, r = srstd;
    u16* wo = wn + (size_t)row * I;
    for (int i = threadIdx.x; i < I; i += 256) wo[i] = f2bu((wr[i] - mean) * r);
}

// ---------------------------------------------------------------------------
// Transpose f32 [b][R][C] -> bf16 [b][C][R].  grid (C/64, R/64, NB), 256 thr.
// ---------------------------------------------------------------------------
__global__ __launch_bounds__(256) void transpose_f2b(const float* __restrict__ in,
                                                     u16* __restrict__ out, int R, int C) {
    __shared__ float tile[64][65];
    int c0 = blockIdx.x * 64, r0 = blockIdx.y * 64, b = blockIdx.z;
    const float* ip = in + (size_t)b * R * C;
    u16* op = out + (size_t)b * R * C;
    int tid = threadIdx.x;
#pragma unroll
    for (int m = 0; m < 16; m++) {
        int id = tid + 256 * m; int r = id >> 6, c = id & 63;
        tile[r][c] = ip[(size_t)(r0 + r) * C + c0 + c];
    }
    __syncthreads();
#pragma unroll
    for (int m = 0; m < 16; m++) {
        int id = tid + 256 * m; int rr = id >> 6, cc = id & 63;
        op[(size_t)(c0 + rr) * R + r0 + cc] = f2bu(tile[cc][rr]);
    }
}

// Transpose bf16 [b][R][C] -> bf16 [b][C][R].
__global__ __launch_bounds__(256) void transpose_b2b(const u16* __restrict__ in,
                                                     u16* __restrict__ out, int R, int C) {
    __shared__ u16 tile[64][65];
    int c0 = blockIdx.x * 64, r0 = blockIdx.y * 64, b = blockIdx.z;
    const u16* ip = in + (size_t)b * R * C;
    u16* op = out + (size_t)b * R * C;
    int tid = threadIdx.x;
#pragma unroll
    for (int m = 0; m < 16; m++) {
        int id = tid + 256 * m; int r = id >> 6, c = id & 63;
        tile[r][c] = ip[(size_t)(r0 + r) * C + c0 + c];
    }
    __syncthreads();
#pragma unroll
    for (int m = 0; m < 16; m++) {
        int id = tid + 256 * m; int rr = id >> 6, cc = id & 63;
        op[(size_t)(c0 + rr) * R + r0 + cc] = tile[cc][rr];
    }
}

// ---------------------------------------------------------------------------
// MFMA projection GEMM: C[b][o][l] = Wn[o][i] @ X[b] (via XT [b][l][i]), +bias,
// mask over l, optional f32 residual, out bf16 OR f32.
// Block 256 (4 waves); 64x64 tile; wave w owns t-cols w*16..w*16+15.
// grid (L/64, O/64, NB)
// ---------------------------------------------------------------------------
__global__ __launch_bounds__(256) void proj_mfma(
    const u16* __restrict__ A, const u16* __restrict__ BT,
    const float* __restrict__ bias, const int* __restrict__ mask,
    const float* __restrict__ resid, u16* __restrict__ outB, float* __restrict__ outF,
    int O, int I, int L) {
    __shared__ u16 at[64][72];   // [o][i]  (A frag: m=lane&15 row, k contiguous)
    __shared__ u16 bt[64][72];   // [l][i]  (B frag: n=lane&15 row, k contiguous)
    int tid = threadIdx.x;
    int w = tid >> 6, lane = tid & 63, quad = lane >> 4, l16 = lane & 15;
    int l0 = blockIdx.x * 64, o0 = blockIdx.y * 64, b = blockIdx.z;
    const u16* Bp = BT + (size_t)b * L * I;

    f32x4 acc[4] = {};
    for (int k0 = 0; k0 < I; k0 += 64) {
        __syncthreads();
#pragma unroll
        for (int m = 0; m < 2; m++) {
            int id = tid + 256 * m; int r = id >> 3, c = (id & 7) * 8;
            *(u16x8*)&at[r][c] = *(const u16x8*)&A[(size_t)(o0 + r) * I + k0 + c];
            *(u16x8*)&bt[r][c] = *(const u16x8*)&Bp[(size_t)(l0 + r) * I + k0 + c];
        }
        __syncthreads();
#pragma unroll
        for (int ks = 0; ks < 64; ks += 32) {
            short8 bf = *(const short8*)&bt[w * 16 + l16][ks + quad * 8];
#pragma unroll
            for (int mt = 0; mt < 4; mt++) {
                short8 af = *(const short8*)&at[mt * 16 + l16][ks + quad * 8];
                acc[mt] = MFMA16(af, bf, acc[mt]);
            }
        }
    }
    int l = l0 + w * 16 + l16;
    int mval = mask[(size_t)b * L + l];
#pragma unroll
    for (int mt = 0; mt < 4; mt++) {
#pragma unroll
        for (int reg = 0; reg < 4; reg++) {
            int o = o0 + mt * 16 + quad * 4 + reg;
            float v = mval ? (acc[mt][reg] + bias[o]) : 0.f;
            size_t off = ((size_t)b * O + o) * L + l;
            if (resid) v += resid[off];
            if (outF) outF[off] = v; else outB[off] = f2bu(v);
        }
    }
}

// ---------------------------------------------------------------------------
// Per-head LayerNorm over DH, bf16 in [b][E][L] -> bf16 out transposed
// per-head [bh][l][d] (contiguous d rows for MFMA fragments).
// ---------------------------------------------------------------------------
__global__ __launch_bounds__(256) void ln_to_T(const u16* __restrict__ y,
                                               const float* __restrict__ g,
                                               const float* __restrict__ be,
                                               u16* __restrict__ outT, int L) {
    int idx = blockIdx.x * 256 + threadIdx.x;   // NB*NH*L threads
    int l = idx % L; int bh = idx / L;
    size_t base = ((size_t)bh * 64) * L + l;    // (b*EE + h*64) * L + l
    float v[DHH]; float s = 0.f;
#pragma unroll
    for (int d = 0; d < DHH; d++) { v[d] = bu2f(y[base + (size_t)d * L]); s += v[d]; }
    float mean = s * (1.f / DHH);
    float s2 = 0.f;
#pragma unroll
    for (int d = 0; d < DHH; d++) { float dv = v[d] - mean; s2 += dv * dv; }
    float r = rsqrtf(s2 * (1.f / DHH) + EPSF);
    u16* o = outT + ((size_t)bh * L + l) * DHH;
#pragma unroll
    for (int d = 0; d < DHH; d++) o[d] = f2bu((v[d] - mean) * r * g[d] + be[d]);
}

// Same LN but in place (for V, layout [b][E][L] kept).
__global__ __launch_bounds__(256) void ln_inplace(u16* __restrict__ y,
                                                  const float* __restrict__ g,
                                                  const float* __restrict__ be, int L) {
    int idx = blockIdx.x * 256 + threadIdx.x;
    int l = idx % L; int bh = idx / L;
    size_t base = ((size_t)bh * 64) * L + l;
    float v[DHH]; float s = 0.f;
#pragma unroll
    for (int d = 0; d < DHH; d++) { v[d] = bu2f(y[base + (size_t)d * L]); s += v[d]; }
    float mean = s * (1.f / DHH);
    float s2 = 0.f;
#pragma unroll
    for (int d = 0; d < DHH; d++) { float dv = v[d] - mean; s2 += dv * dv; }
    float r = rsqrtf(s2 * (1.f / DHH) + EPSF);
#pragma unroll
    for (int d = 0; d < DHH; d++) y[base + (size_t)d * L] = f2bu((v[d] - mean) * r * g[d] + be[d]);
}

// ---------------------------------------------------------------------------
// Pass A: l_s = sum_t mask[t]*exp(sc[s][t]) ; sc = (K^T Q)/256 via MFMA.
// Scores are bounded (|sc| <= ~16) so no max subtraction is needed; masked-t
// terms contribute exactly 0 (matches exp(-1e9 - m) = 0 in the reference).
// grid (SS/64, NH, NB), 256 thr.
// ---------------------------------------------------------------------------
__global__ __launch_bounds__(256) void attn_stats_mfma(
    const u16* __restrict__ qT, const u16* __restrict__ kT,
    const int* __restrict__ mask, float* __restrict__ lrow) {
    __shared__ u16 kt[64][72];   // [s][d]
    __shared__ u16 qt[64][72];   // [t][d]
    __shared__ float lp[4][64];
    int tid = threadIdx.x;
    int w = tid >> 6, lane = tid & 63, quad = lane >> 4, l16 = lane & 15;
    int s0 = blockIdx.x * 64, h = blockIdx.y, b = blockIdx.z;
    int head = b * NH + h;
    const u16* kp = kT + (size_t)head * SS * DHH;
    const u16* qp = qT + (size_t)head * TT * DHH;
    const int* mk = mask + (size_t)b * TT;
#pragma unroll
    for (int m = 0; m < 2; m++) {
        int id = tid + 256 * m; int r = id >> 3, c = (id & 7) * 8;
        *(u16x8*)&kt[r][c] = *(const u16x8*)&kp[(size_t)(s0 + r) * DHH + c];
    }
    float rl[4][4] = {};
    for (int t0 = 0; t0 < TT; t0 += 64) {
        __syncthreads();
#pragma unroll
        for (int m = 0; m < 2; m++) {
            int id = tid + 256 * m; int r = id >> 3, c = (id & 7) * 8;
            *(u16x8*)&qt[r][c] = *(const u16x8*)&qp[(size_t)(t0 + r) * DHH + c];
        }
        __syncthreads();
        int mval = mk[t0 + w * 16 + l16];
        f32x4 acc[4] = {};
#pragma unroll
        for (int ks = 0; ks < 64; ks += 32) {
            short8 bf = *(const short8*)&qt[w * 16 + l16][ks + quad * 8];
#pragma unroll
            for (int mt = 0; mt < 4; mt++) {
                short8 af = *(const short8*)&kt[mt * 16 + l16][ks + quad * 8];
                acc[mt] = MFMA16(af, bf, acc[mt]);
            }
        }
        if (mval) {
#pragma unroll
            for (int mt = 0; mt < 4; mt++)
#pragma unroll
                for (int reg = 0; reg < 4; reg++)
                    rl[mt][reg] += __expf(acc[mt][reg] * SCALE_INV);
        }
    }
    // reduce across the 16 lanes (l16) sharing each s-row, then across waves
#pragma unroll
    for (int mt = 0; mt < 4; mt++) {
#pragma unroll
        for (int reg = 0; reg < 4; reg++) {
            float v = rl[mt][reg];
            v += __shfl_xor(v, 1); v += __shfl_xor(v, 2);
            v += __shfl_xor(v, 4); v += __shfl_xor(v, 8);
            if (l16 == 0) lp[w][mt * 16 + quad * 4 + reg] = v;
        }
    }
    __syncthreads();
    if (tid < 64)
        lrow[(size_t)head * SS + s0 + tid] = lp[0][tid] + lp[1][tid] + lp[2][tid] + lp[3][tid];
}

// ---------------------------------------------------------------------------
// Pass B: out[d][t] = sum_s V[d][s] * P[s][t];
// P = mask_ctx[s]*mask[t]*exp(sc)/l_s; sc recomputed via identical MFMA tiling
// (bit-exact vs pass A). P round-trips LDS (C-layout -> B-operand layout).
// grid (TT/64, NH, NB)
// ---------------------------------------------------------------------------
__global__ __launch_bounds__(256) void attn_pv_mfma(
    const u16* __restrict__ qT, const u16* __restrict__ kT, const u16* __restrict__ vb,
    const int* __restrict__ mask, const int* __restrict__ mask_ctx,
    const float* __restrict__ lrow, u16* __restrict__ outb) {
    __shared__ u16 qt[64][72];   // [t][d]
    __shared__ u16 kt[64][72];   // [s][d]
    __shared__ u16 vt[64][72];   // [d][s]
    __shared__ u16 pt[64][72];   // [t][s]  (B-operand source for PV)
    __shared__ float slr[64];
    __shared__ int smc[64];
    int tid = threadIdx.x;
    int w = tid >> 6, lane = tid & 63, quad = lane >> 4, l16 = lane & 15;
    int t0 = blockIdx.x * 64, h = blockIdx.y, b = blockIdx.z;
    int head = b * NH + h;
    const u16* qp = qT + (size_t)head * TT * DHH;
    const u16* kp = kT + (size_t)head * SS * DHH;
    const u16* vp = vb + ((size_t)head * DHH) * SS;   // rows d of [b][E][S]
#pragma unroll
    for (int m = 0; m < 2; m++) {
        int id = tid + 256 * m; int r = id >> 3, c = (id & 7) * 8;
        *(u16x8*)&qt[r][c] = *(const u16x8*)&qp[(size_t)(t0 + r) * DHH + c];
    }
    int mkv = mask[(size_t)b * TT + t0 + w * 16 + l16];
    const float* lr = lrow + (size_t)head * SS;
    const int* mc = mask_ctx + (size_t)b * SS;

    f32x4 oacc[4] = {};
    for (int s0 = 0; s0 < SS; s0 += 64) {
        __syncthreads();
#pragma unroll
        for (int m = 0; m < 2; m++) {
            int id = tid + 256 * m; int r = id >> 3, c = (id & 7) * 8;
            *(u16x8*)&kt[r][c] = *(const u16x8*)&kp[(size_t)(s0 + r) * DHH + c];
            *(u16x8*)&vt[r][c] = *(const u16x8*)&vp[(size_t)r * SS + s0 + c];
        }
        if (tid < 64) { slr[tid] = lr[s0 + tid]; smc[tid] = mc[s0 + tid]; }
        __syncthreads();
        // scores tile (identical to pass A ordering)
        f32x4 acc[4] = {};
#pragma unroll
        for (int ks = 0; ks < 64; ks += 32) {
            short8 bf = *(const short8*)&qt[w * 16 + l16][ks + quad * 8];
#pragma unroll
            for (int mt = 0; mt < 4; mt++) {
                short8 af = *(const short8*)&kt[mt * 16 + l16][ks + quad * 8];
                acc[mt] = MFMA16(af, bf, acc[mt]);
            }
        }
        // P -> pt[t][s]
#pragma unroll
        for (int mt = 0; mt < 4; mt++) {
#pragma unroll
            for (int reg = 0; reg < 4; reg++) {
                int sl = mt * 16 + quad * 4 + reg;
                float p = 0.f;
                if (mkv && smc[sl]) p = __expf(acc[mt][reg] * SCALE_INV) / slr[sl];
                pt[w * 16 + l16][sl] = f2bu(p);
            }
        }
        __syncthreads();
        // out += V @ P
#pragma unroll
        for (int ks = 0; ks < 64; ks += 32) {
            short8 bf = *(const short8*)&pt[w * 16 + l16][ks + quad * 8];
#pragma unroll
            for (int mt = 0; mt < 4; mt++) {
                short8 af = *(const short8*)&vt[mt * 16 + l16][ks + quad * 8];
                oacc[mt] = MFMA16(af, bf, oacc[mt]);
            }
        }
    }
    int t = t0 + w * 16 + l16;
#pragma unroll
    for (int mt = 0; mt < 4; mt++) {
#pragma unroll
        for (int reg = 0; reg < 4; reg++) {
            int d = mt * 16 + quad * 4 + reg;
            outb[((size_t)head * DHH + d) * TT + t] = f2bu(oacc[mt][reg]);
        }
    }
}

// ---------------------------------------------------------------------------
extern "C" void kernel_launch(void* const* d_in, const int* in_sizes, int n_in,
                              void* d_out, int out_size, void* d_ws, size_t ws_size,
                              hipStream_t stream) {
    const float* x        = (const float*)d_in[0];
    const float* ctx      = (const float*)d_in[1];
    const int*   mask     = (const int*)d_in[2];
    const int*   mask_ctx = (const int*)d_in[3];
    const float* qw  = (const float*)d_in[4];
    const float* qbi = (const float*)d_in[5];
    const float* kw  = (const float*)d_in[6];
    const float* kbi = (const float*)d_in[7];
    const float* vw  = (const float*)d_in[8];
    const float* vbi = (const float*)d_in[9];
    const float* ow  = (const float*)d_in[10];
    const float* obi = (const float*)d_in[11];
    const float* gq = (const float*)d_in[12];
    const float* bq = (const float*)d_in[13];
    const float* gk = (const float*)d_in[14];
    const float* bk = (const float*)d_in[15];
    const float* gv = (const float*)d_in[16];
    const float* bv = (const float*)d_in[17];

    // workspace carve (~61.5 MB)
    u16* p = (u16*)d_ws;
    u16* wqn = p; p += (size_t)EE * EE;          // bf16 normalized weights
    u16* wkn = p; p += (size_t)EE * CCH;
    u16* wvn = p; p += (size_t)EE * CCH;
    u16* won = p; p += (size_t)EE * EE;
    u16* xT  = p; p += (size_t)NB * TT * EE;     // [b][t][e]
    u16* cT  = p; p += (size_t)NB * SS * CCH;    // [b][s][c]
    u16* yq  = p; p += (size_t)NB * EE * TT;     // q proj out; later reused as a_s
    u16* yk  = p; p += (size_t)NB * EE * SS;     // k proj out; later reused as aT
    u16* yv  = p; p += (size_t)NB * EE * SS;     // v proj out, LN'd in place
    u16* qT  = p; p += (size_t)NB * NH * TT * DHH;  // [bh][t][d]
    u16* kT  = p; p += (size_t)NB * NH * SS * DHH;  // [bh][s][d]
    float* lrow = (float*)p;                     // [bh][s]
    u16* a_s = yq;                               // attn out [b][E][T] (yq dead)
    u16* aT  = yk;                               // attn out transposed (yk dead)

    // 1) weight standardization -> bf16
    ws_norm_kernel<<<EE, 256, 0, stream>>>(qw, wqn, EE);
    ws_norm_kernel<<<EE, 256, 0, stream>>>(kw, wkn, CCH);
    ws_norm_kernel<<<EE, 256, 0, stream>>>(vw, wvn, CCH);
    ws_norm_kernel<<<EE, 256, 0, stream>>>(ow, won, EE);

    // 2) transpose inputs to [l][i] bf16
    transpose_f2b<<<dim3(TT / 64, EE / 64, NB), 256, 0, stream>>>(x, xT, EE, TT);
    transpose_f2b<<<dim3(SS / 64, CCH / 64, NB), 256, 0, stream>>>(ctx, cT, CCH, SS);

    // 3) q/k/v projections (MFMA, +bias +mask) -> bf16
    proj_mfma<<<dim3(TT / 64, EE / 64, NB), 256, 0, stream>>>(
        wqn, xT, qbi, mask, nullptr, yq, nullptr, EE, EE, TT);
    proj_mfma<<<dim3(SS / 64, EE / 64, NB), 256, 0, stream>>>(
        wkn, cT, kbi, mask_ctx, nullptr, yk, nullptr, EE, CCH, SS);
    proj_mfma<<<dim3(SS / 64, EE / 64, NB), 256, 0, stream>>>(
        wvn, cT, vbi, mask_ctx, nullptr, yv, nullptr, EE, CCH, SS);

    // 4) per-head LN: q,k -> transposed [bh][l][d]; v in place
    ln_to_T<<<(NB * NH * TT) / 256, 256, 0, stream>>>(yq, gq, bq, qT, TT);
    ln_to_T<<<(NB * NH * SS) / 256, 256, 0, stream>>>(yk, gk, bk, kT, SS);
    ln_inplace<<<(NB * NH * SS) / 256, 256, 0, stream>>>(yv, gv, bv, SS);

    // 5) attention (MFMA both passes)
    attn_stats_mfma<<<dim3(SS / 64, NH, NB), 256, 0, stream>>>(qT, kT, mask, lrow);
    attn_pv_mfma<<<dim3(TT / 64, NH, NB), 256, 0, stream>>>(qT, kT, yv, mask, mask_ctx,
                                                            lrow, a_s);

    // 6) transpose attn out, then o-proj (+mask +f32 residual) -> f32 d_out
    transpose_b2b<<<dim3(TT / 64, EE / 64, NB), 256, 0, stream>>>(a_s, aT, EE, TT);
    proj_mfma<<<dim3(TT / 64, EE / 64, NB), 256, 0, stream>>>(
        won, aT, obi, mask, x, nullptr, (float*)d_out, EE, EE, TT);
}

// Round 4
// 347.534 us; speedup vs baseline: 7.2683x; 1.0924x over previous
//
#include <hip/hip_runtime.h>

// Problem constants (B=4, T=S=1024, E=1024, CTX=768, H=16, DH=64)
#define NB 4
#define TT 1024
#define SS 1024
#define EE 1024
#define CCH 768
#define NH 16
#define DHH 64
#define EPSF 1e-5f
// SCALE = 1024 // (16**0.5) = 256.  Fold 1/256 * log2(e) into q so that
// exp(score/256) == exp2(q'.k) with a single v_exp_f32.
#define QSCALE (1.4426950408889634f / 256.0f)

typedef unsigned short u16;
typedef __attribute__((ext_vector_type(8))) short short8;       // MFMA A/B frag
typedef __attribute__((ext_vector_type(8))) unsigned short u16x8;
typedef __attribute__((ext_vector_type(4))) unsigned short u16x4;
typedef __attribute__((ext_vector_type(4))) float f32x4;        // MFMA C/D frag

__device__ __forceinline__ u16 f2bu(float f) {
    union { float f; unsigned u; } x; x.f = f;
    unsigned r = x.u + 0x7fffu + ((x.u >> 16) & 1u);
    return (u16)(r >> 16);
}
__device__ __forceinline__ float bu2f(u16 u) {
    union { unsigned u; float f; } x; x.u = ((unsigned)u) << 16; return x.f;
}

#if __has_builtin(__builtin_amdgcn_exp2f)
#define EXP2(x) __builtin_amdgcn_exp2f(x)
#else
#define EXP2(x) exp2f(x)
#endif

#define MFMA16(a, b, c) __builtin_amdgcn_mfma_f32_16x16x32_bf16((a), (b), (c), 0, 0, 0)

// ---------------------------------------------------------------------------
// Weight standardization: w [O,I] f32 -> wn [O,I] bf16. One block per row.
// ---------------------------------------------------------------------------
__global__ __launch_bounds__(256) void ws_norm_kernel(const float* __restrict__ w,
                                                      u16* __restrict__ wn, int I) {
    int row = blockIdx.x;
    const float* wr = w + (size_t)row * I;
    float s = 0.f, s2 = 0.f;
    for (int i = threadIdx.x; i < I; i += 256) { float v = wr[i]; s += v; s2 += v * v; }
#pragma unroll
    for (int off = 32; off > 0; off >>= 1) { s += __shfl_down(s, off); s2 += __shfl_down(s2, off); }
    __shared__ float sa[4], sb[4], smean, srstd;
    int wid = threadIdx.x >> 6;
    if ((threadIdx.x & 63) == 0) { sa[wid] = s; sb[wid] = s2; }
    __syncthreads();
    if (threadIdx.x == 0) {
        float ts = sa[0] + sa[1] + sa[2] + sa[3];
        float ts2 = sb[0] + sb[1] + sb[2] + sb[3];
        float mean = ts / (float)I;
        float var = ts2 / (float)I - mean * mean;
        smean = mean; srstd = rsqrtf(var + EPSF);
    }
    __syncthreads();
    float mean = smean, r = srstd;
    u16* wo = wn + (size_t)row * I;
    for (int i = threadIdx.x; i < I; i += 256) wo[i] = f2bu((wr[i] - mean) * r);
}

// ---------------------------------------------------------------------------
// Transpose f32 [b][R][C] -> bf16 [b][C][R].  grid (C/64, R/64, NB), 256 thr.
// ---------------------------------------------------------------------------
__global__ __launch_bounds__(256) void transpose_f2b(const float* __restrict__ in,
                                                     u16* __restrict__ out, int R, int C) {
    __shared__ float tile[64][65];
    int c0 = blockIdx.x * 64, r0 = blockIdx.y * 64, b = blockIdx.z;
    const float* ip = in + (size_t)b * R * C;
    u16* op = out + (size_t)b * R * C;
    int tid = threadIdx.x;
#pragma unroll
    for (int m = 0; m < 16; m++) {
        int id = tid + 256 * m; int r = id >> 6, c = id & 63;
        tile[r][c] = ip[(size_t)(r0 + r) * C + c0 + c];
    }
    __syncthreads();
#pragma unroll
    for (int m = 0; m < 16; m++) {
        int id = tid + 256 * m; int rr = id >> 6, cc = id & 63;
        op[(size_t)(c0 + rr) * R + r0 + cc] = f2bu(tile[cc][rr]);
    }
}

// ---------------------------------------------------------------------------
// MFMA projection GEMM, 128x128 tile, 4 waves, each wave a 64x64 quadrant
// (4x4 16x16x32 frags). C[b][o][l] = Wn[o][:] . XT[b][l][:], +bias, mask over l,
// optional f32 residual; bf16 or f32 out. grid (L/128, O/128, NB), 256 thr.
// ---------------------------------------------------------------------------
__global__ __launch_bounds__(256) void proj_mfma128(
    const u16* __restrict__ A, const u16* __restrict__ BT,
    const float* __restrict__ bias, const int* __restrict__ mask,
    const float* __restrict__ resid, u16* __restrict__ outB, float* __restrict__ outF,
    int O, int I, int L) {
    __shared__ u16 at[128][72];   // [o][k]
    __shared__ u16 bt[128][72];   // [l][k]
    int tid = threadIdx.x;
    int w = tid >> 6, lane = tid & 63, quad = lane >> 4, l16 = lane & 15;
    int wm = w & 1, wn = w >> 1;           // wave quadrant: rows wm*64, cols wn*64
    int l0 = blockIdx.x * 128, o0 = blockIdx.y * 128, b = blockIdx.z;
    const u16* Bp = BT + (size_t)b * L * I;

    f32x4 acc[4][4] = {};
    for (int k0 = 0; k0 < I; k0 += 64) {
        __syncthreads();
#pragma unroll
        for (int m = 0; m < 4; m++) {
            int id = tid + 256 * m;           // 1024 chunks of 8 u16
            int r = id >> 3, c = (id & 7) * 8;
            *(u16x8*)&at[r][c] = *(const u16x8*)&A[(size_t)(o0 + r) * I + k0 + c];
            *(u16x8*)&bt[r][c] = *(const u16x8*)&Bp[(size_t)(l0 + r) * I + k0 + c];
        }
        __syncthreads();
#pragma unroll
        for (int ks = 0; ks < 64; ks += 32) {
            short8 af[4], bf[4];
#pragma unroll
            for (int i = 0; i < 4; i++) {
                af[i] = *(const short8*)&at[wm * 64 + i * 16 + l16][ks + quad * 8];
                bf[i] = *(const short8*)&bt[wn * 64 + i * 16 + l16][ks + quad * 8];
            }
#pragma unroll
            for (int mt = 0; mt < 4; mt++)
#pragma unroll
                for (int nt = 0; nt < 4; nt++)
                    acc[mt][nt] = MFMA16(af[mt], bf[nt], acc[mt][nt]);
        }
    }
    const int* mrow = mask + (size_t)b * L;
#pragma unroll
    for (int nt = 0; nt < 4; nt++) {
        int l = l0 + wn * 64 + nt * 16 + l16;
        int mval = mrow[l];
#pragma unroll
        for (int mt = 0; mt < 4; mt++) {
#pragma unroll
            for (int reg = 0; reg < 4; reg++) {
                int o = o0 + wm * 64 + mt * 16 + quad * 4 + reg;
                float v = mval ? (acc[mt][nt][reg] + bias[o]) : 0.f;
                size_t off = ((size_t)b * O + o) * L + l;
                if (resid) v += resid[off];
                if (outF) outF[off] = v; else outB[off] = f2bu(v);
            }
        }
    }
}

// ---------------------------------------------------------------------------
// Per-head LayerNorm over DH, bf16 in [b][E][L] -> bf16 out transposed
// per-head [bh][l][d], with a folded output scale (QSCALE for q, 1 for k).
// ---------------------------------------------------------------------------
__global__ __launch_bounds__(256) void ln_to_T(const u16* __restrict__ y,
                                               const float* __restrict__ g,
                                               const float* __restrict__ be,
                                               u16* __restrict__ outT, int L, float scale) {
    int idx = blockIdx.x * 256 + threadIdx.x;   // NB*NH*L threads
    int l = idx % L; int bh = idx / L;
    size_t base = ((size_t)bh * 64) * L + l;
    float v[DHH]; float s = 0.f;
#pragma unroll
    for (int d = 0; d < DHH; d++) { v[d] = bu2f(y[base + (size_t)d * L]); s += v[d]; }
    float mean = s * (1.f / DHH);
    float s2 = 0.f;
#pragma unroll
    for (int d = 0; d < DHH; d++) { float dv = v[d] - mean; s2 += dv * dv; }
    float r = rsqrtf(s2 * (1.f / DHH) + EPSF);
    u16* o = outT + ((size_t)bh * L + l) * DHH;
#pragma unroll
    for (int d = 0; d < DHH; d++)
        o[d] = f2bu(((v[d] - mean) * r * g[d] + be[d]) * scale);
}

// ---------------------------------------------------------------------------
// V LayerNorm + fold mask_ctx[s]/l_s into V (in place, layout [b][E][S]).
// Eliminates all per-score division in pass B. l==0 guard matches the
// reference's uniform-softmax-then-zero edge case (P column is 0 anyway).
// ---------------------------------------------------------------------------
__global__ __launch_bounds__(256) void ln_v_scale(u16* __restrict__ y,
                                                  const float* __restrict__ g,
                                                  const float* __restrict__ be,
                                                  const int* __restrict__ mask_ctx,
                                                  const float* __restrict__ lrow, int L) {
    int idx = blockIdx.x * 256 + threadIdx.x;
    int l = idx % L; int bh = idx / L; int b = bh / NH;
    size_t base = ((size_t)bh * 64) * L + l;
    float v[DHH]; float s = 0.f;
#pragma unroll
    for (int d = 0; d < DHH; d++) { v[d] = bu2f(y[base + (size_t)d * L]); s += v[d]; }
    float mean = s * (1.f / DHH);
    float s2 = 0.f;
#pragma unroll
    for (int d = 0; d < DHH; d++) { float dv = v[d] - mean; s2 += dv * dv; }
    float r = rsqrtf(s2 * (1.f / DHH) + EPSF);
    float lv = lrow[(size_t)bh * L + l];
    float wsc = (mask_ctx[(size_t)b * L + l] != 0 && lv > 0.f) ? (1.f / lv) : 0.f;
#pragma unroll
    for (int d = 0; d < DHH; d++)
        y[base + (size_t)d * L] = f2bu(((v[d] - mean) * r * g[d] + be[d]) * wsc);
}

// ---------------------------------------------------------------------------
// Pass A: l_s = sum_t mask[t] * exp2(q'.k)  (q pre-scaled by log2e/256).
// grid (SS/64, NH, NB), 256 thr.
// ---------------------------------------------------------------------------
__global__ __launch_bounds__(256) void attn_stats_mfma(
    const u16* __restrict__ qT, const u16* __restrict__ kT,
    const int* __restrict__ mask, float* __restrict__ lrow) {
    __shared__ u16 kt[64][72];   // [s][d]
    __shared__ u16 qt[64][72];   // [t][d]
    __shared__ float lp[4][64];
    int tid = threadIdx.x;
    int w = tid >> 6, lane = tid & 63, quad = lane >> 4, l16 = lane & 15;
    int s0 = blockIdx.x * 64, h = blockIdx.y, b = blockIdx.z;
    int head = b * NH + h;
    const u16* kp = kT + (size_t)head * SS * DHH;
    const u16* qp = qT + (size_t)head * TT * DHH;
    const int* mk = mask + (size_t)b * TT;
#pragma unroll
    for (int m = 0; m < 2; m++) {
        int id = tid + 256 * m; int r = id >> 3, c = (id & 7) * 8;
        *(u16x8*)&kt[r][c] = *(const u16x8*)&kp[(size_t)(s0 + r) * DHH + c];
    }
    float rl[4][4] = {};
    for (int t0 = 0; t0 < TT; t0 += 64) {
        __syncthreads();
#pragma unroll
        for (int m = 0; m < 2; m++) {
            int id = tid + 256 * m; int r = id >> 3, c = (id & 7) * 8;
            *(u16x8*)&qt[r][c] = *(const u16x8*)&qp[(size_t)(t0 + r) * DHH + c];
        }
        __syncthreads();
        int mval = mk[t0 + w * 16 + l16];
        f32x4 acc[4] = {};
#pragma unroll
        for (int ks = 0; ks < 64; ks += 32) {
            short8 bf = *(const short8*)&qt[w * 16 + l16][ks + quad * 8];
#pragma unroll
            for (int mt = 0; mt < 4; mt++) {
                short8 af = *(const short8*)&kt[mt * 16 + l16][ks + quad * 8];
                acc[mt] = MFMA16(af, bf, acc[mt]);
            }
        }
        if (mval) {
#pragma unroll
            for (int mt = 0; mt < 4; mt++)
#pragma unroll
                for (int reg = 0; reg < 4; reg++)
                    rl[mt][reg] += EXP2(acc[mt][reg]);
        }
    }
#pragma unroll
    for (int mt = 0; mt < 4; mt++) {
#pragma unroll
        for (int reg = 0; reg < 4; reg++) {
            float v = rl[mt][reg];
            v += __shfl_xor(v, 1); v += __shfl_xor(v, 2);
            v += __shfl_xor(v, 4); v += __shfl_xor(v, 8);
            if (l16 == 0) lp[w][mt * 16 + quad * 4 + reg] = v;
        }
    }
    __syncthreads();
    if (tid < 64)
        lrow[(size_t)head * SS + s0 + tid] = lp[0][tid] + lp[1][tid] + lp[2][tid] + lp[3][tid];
}

// ---------------------------------------------------------------------------
// Pass B: out[t][e] = sum_s V'[d][s] * Praw[s][t], Praw = mask[t]*exp2(q'.k)
// (V' already carries mask_ctx/l). Score MFMA order is bit-identical to pass A.
// Output is LDS-transposed and written directly as aT [b][t][e=h*64+d].
// grid (TT/64, NH, NB)
// ---------------------------------------------------------------------------
__global__ __launch_bounds__(256) void attn_pv_mfma(
    const u16* __restrict__ qT, const u16* __restrict__ kT, const u16* __restrict__ vs,
    const int* __restrict__ mask, u16* __restrict__ aT) {
    __shared__ u16 qt[64][72];   // [t][d]
    __shared__ u16 kt[64][72];   // [s][d]
    __shared__ u16 vt[64][72];   // [d][s]
    __shared__ u16 pt[64][72];   // [t][s] (B-operand for PV); reused for out tile
    int tid = threadIdx.x;
    int w = tid >> 6, lane = tid & 63, quad = lane >> 4, l16 = lane & 15;
    int t0 = blockIdx.x * 64, h = blockIdx.y, b = blockIdx.z;
    int head = b * NH + h;
    const u16* qp = qT + (size_t)head * TT * DHH;
    const u16* kp = kT + (size_t)head * SS * DHH;
    const u16* vp = vs + ((size_t)head * DHH) * SS;
#pragma unroll
    for (int m = 0; m < 2; m++) {
        int id = tid + 256 * m; int r = id >> 3, c = (id & 7) * 8;
        *(u16x8*)&qt[r][c] = *(const u16x8*)&qp[(size_t)(t0 + r) * DHH + c];
    }
    int mkv = mask[(size_t)b * TT + t0 + w * 16 + l16];

    f32x4 oacc[4] = {};
    for (int s0 = 0; s0 < SS; s0 += 64) {
        __syncthreads();
#pragma unroll
        for (int m = 0; m < 2; m++) {
            int id = tid + 256 * m; int r = id >> 3, c = (id & 7) * 8;
            *(u16x8*)&kt[r][c] = *(const u16x8*)&kp[(size_t)(s0 + r) * DHH + c];
            *(u16x8*)&vt[r][c] = *(const u16x8*)&vp[(size_t)r * SS + s0 + c];
        }
        __syncthreads();
        // scores tile: D[row=s][col=t], identical accumulation order to pass A
        f32x4 acc[4] = {};
#pragma unroll
        for (int ks = 0; ks < 64; ks += 32) {
            short8 bf = *(const short8*)&qt[w * 16 + l16][ks + quad * 8];
#pragma unroll
            for (int mt = 0; mt < 4; mt++) {
                short8 af = *(const short8*)&kt[mt * 16 + l16][ks + quad * 8];
                acc[mt] = MFMA16(af, bf, acc[mt]);
            }
        }
        // Praw -> pt[t][s]
#pragma unroll
        for (int mt = 0; mt < 4; mt++) {
#pragma unroll
            for (int reg = 0; reg < 4; reg++) {
                int sl = mt * 16 + quad * 4 + reg;
                float p = mkv ? EXP2(acc[mt][reg]) : 0.f;
                pt[w * 16 + l16][sl] = f2bu(p);
            }
        }
        __syncthreads();
        // out += V' @ Praw  : D[row=d][col=t]
#pragma unroll
        for (int ks = 0; ks < 64; ks += 32) {
            short8 bf = *(const short8*)&pt[w * 16 + l16][ks + quad * 8];
#pragma unroll
            for (int mt = 0; mt < 4; mt++) {
                short8 af = *(const short8*)&vt[mt * 16 + l16][ks + quad * 8];
                oacc[mt] = MFMA16(af, bf, oacc[mt]);
            }
        }
    }
    // transpose out tile via LDS (reuse pt as ot[t][d]) -> aT[b][t][h*64+d]
    __syncthreads();
    int tl = w * 16 + l16;
#pragma unroll
    for (int mt = 0; mt < 4; mt++) {
        u16x4 pk;
#pragma unroll
        for (int reg = 0; reg < 4; reg++) pk[reg] = f2bu(oacc[mt][reg]);
        *(u16x4*)&pt[tl][mt * 16 + quad * 4] = pk;
    }
    __syncthreads();
#pragma unroll
    for (int i = 0; i < 2; i++) {
        int id = tid * 2 + i;                  // 512 chunks of 8 u16 (64t x 64d)
        int r = id >> 3, c = (id & 7) * 8;
        *(u16x8*)&aT[((size_t)b * TT + t0 + r) * EE + h * 64 + c] =
            *(const u16x8*)&pt[r][c];
    }
}

// ---------------------------------------------------------------------------
extern "C" void kernel_launch(void* const* d_in, const int* in_sizes, int n_in,
                              void* d_out, int out_size, void* d_ws, size_t ws_size,
                              hipStream_t stream) {
    const float* x        = (const float*)d_in[0];
    const float* ctx      = (const float*)d_in[1];
    const int*   mask     = (const int*)d_in[2];
    const int*   mask_ctx = (const int*)d_in[3];
    const float* qw  = (const float*)d_in[4];
    const float* qbi = (const float*)d_in[5];
    const float* kw  = (const float*)d_in[6];
    const float* kbi = (const float*)d_in[7];
    const float* vw  = (const float*)d_in[8];
    const float* vbi = (const float*)d_in[9];
    const float* ow  = (const float*)d_in[10];
    const float* obi = (const float*)d_in[11];
    const float* gq = (const float*)d_in[12];
    const float* bq = (const float*)d_in[13];
    const float* gk = (const float*)d_in[14];
    const float* bk = (const float*)d_in[15];
    const float* gv = (const float*)d_in[16];
    const float* bv = (const float*)d_in[17];

    // workspace carve (~61.5 MB)
    u16* p = (u16*)d_ws;
    u16* wqn = p; p += (size_t)EE * EE;
    u16* wkn = p; p += (size_t)EE * CCH;
    u16* wvn = p; p += (size_t)EE * CCH;
    u16* won = p; p += (size_t)EE * EE;
    u16* xT  = p; p += (size_t)NB * TT * EE;     // [b][t][e]
    u16* cT  = p; p += (size_t)NB * SS * CCH;    // [b][s][c]
    u16* yq  = p; p += (size_t)NB * EE * TT;     // q proj out; reused as aT later
    u16* yk  = p; p += (size_t)NB * EE * SS;     // k proj out
    u16* yv  = p; p += (size_t)NB * EE * SS;     // v proj out, LN+scale in place
    u16* qT  = p; p += (size_t)NB * NH * TT * DHH;  // [bh][t][d], pre-scaled
    u16* kT  = p; p += (size_t)NB * NH * SS * DHH;  // [bh][s][d]
    float* lrow = (float*)p;                     // [bh][s]
    u16* aT = yq;                                // attn out [b][t][e] (yq dead)

    // 1) weight standardization -> bf16
    ws_norm_kernel<<<EE, 256, 0, stream>>>(qw, wqn, EE);
    ws_norm_kernel<<<EE, 256, 0, stream>>>(kw, wkn, CCH);
    ws_norm_kernel<<<EE, 256, 0, stream>>>(vw, wvn, CCH);
    ws_norm_kernel<<<EE, 256, 0, stream>>>(ow, won, EE);

    // 2) transpose inputs to [l][i] bf16
    transpose_f2b<<<dim3(TT / 64, EE / 64, NB), 256, 0, stream>>>(x, xT, EE, TT);
    transpose_f2b<<<dim3(SS / 64, CCH / 64, NB), 256, 0, stream>>>(ctx, cT, CCH, SS);

    // 3) q/k/v projections (128x128 MFMA, +bias +mask) -> bf16
    proj_mfma128<<<dim3(TT / 128, EE / 128, NB), 256, 0, stream>>>(
        wqn, xT, qbi, mask, nullptr, yq, nullptr, EE, EE, TT);
    proj_mfma128<<<dim3(SS / 128, EE / 128, NB), 256, 0, stream>>>(
        wkn, cT, kbi, mask_ctx, nullptr, yk, nullptr, EE, CCH, SS);
    proj_mfma128<<<dim3(SS / 128, EE / 128, NB), 256, 0, stream>>>(
        wvn, cT, vbi, mask_ctx, nullptr, yv, nullptr, EE, CCH, SS);

    // 4) per-head LN: q (folded exp2/scale), k -> [bh][l][d]
    ln_to_T<<<(NB * NH * TT) / 256, 256, 0, stream>>>(yq, gq, bq, qT, TT, QSCALE);
    ln_to_T<<<(NB * NH * SS) / 256, 256, 0, stream>>>(yk, gk, bk, kT, SS, 1.0f);

    // 5) softmax denominators, then fold mask_ctx/l into V's LN
    attn_stats_mfma<<<dim3(SS / 64, NH, NB), 256, 0, stream>>>(qT, kT, mask, lrow);
    ln_v_scale<<<(NB * NH * SS) / 256, 256, 0, stream>>>(yv, gv, bv, mask_ctx, lrow, SS);

    // 6) PV pass -> aT [b][t][e] directly
    attn_pv_mfma<<<dim3(TT / 64, NH, NB), 256, 0, stream>>>(qT, kT, yv, mask, aT);

    // 7) o-proj (+mask +f32 residual) -> f32 d_out
    proj_mfma128<<<dim3(TT / 128, EE / 128, NB), 256, 0, stream>>>(
        won, aT, obi, mask, x, nullptr, (float*)d_out, EE, EE, TT);
}

// Round 5
// 275.310 us; speedup vs baseline: 9.1750x; 1.2623x over previous
//
#include <hip/hip_runtime.h>

// Problem constants (B=4, T=S=1024, E=1024, CTX=768, H=16, DH=64)
#define NB 4
#define TT 1024
#define SS 1024
#define EE 1024
#define CCH 768
#define NH 16
#define DHH 64
#define EPSF 1e-5f
// SCALE = 1024 // (16**0.5) = 256.  Fold 1/256 * log2(e) into q so that
// exp(score/256) == exp2(q'.k) with a single v_exp_f32.
#define QSCALE (1.4426950408889634f / 256.0f)

typedef unsigned short u16;
typedef __attribute__((ext_vector_type(8))) short short8;       // MFMA A/B frag
typedef __attribute__((ext_vector_type(8))) unsigned short u16x8;
typedef __attribute__((ext_vector_type(4))) unsigned short u16x4;
typedef __attribute__((ext_vector_type(4))) float f32x4;        // MFMA C/D frag

__device__ __forceinline__ u16 f2bu(float f) {
    union { float f; unsigned u; } x; x.f = f;
    unsigned r = x.u + 0x7fffu + ((x.u >> 16) & 1u);
    return (u16)(r >> 16);
}
__device__ __forceinline__ float bu2f(u16 u) {
    union { unsigned u; float f; } x; x.u = ((unsigned)u) << 16; return x.f;
}

#if __has_builtin(__builtin_amdgcn_exp2f)
#define EXP2(x) __builtin_amdgcn_exp2f(x)
#else
#define EXP2(x) exp2f(x)
#endif

#define MFMA16(a, b, c) __builtin_amdgcn_mfma_f32_16x16x32_bf16((a), (b), (c), 0, 0, 0)

// ---------------------------------------------------------------------------
// Weight standardization, all 4 matrices in one dispatch.
// grid (1024, 4): one block per row, blockIdx.y selects the matrix.
// ---------------------------------------------------------------------------
__global__ __launch_bounds__(256) void ws_norm4(
    const float* __restrict__ qw, const float* __restrict__ kw,
    const float* __restrict__ vw, const float* __restrict__ ow,
    u16* __restrict__ wqn, u16* __restrict__ wkn,
    u16* __restrict__ wvn, u16* __restrict__ won) {
    int mat = blockIdx.y;
    const float* w = mat == 0 ? qw : (mat == 1 ? kw : (mat == 2 ? vw : ow));
    u16* wn = mat == 0 ? wqn : (mat == 1 ? wkn : (mat == 2 ? wvn : won));
    int I = (mat == 1 || mat == 2) ? CCH : EE;
    int row = blockIdx.x;
    const float* wr = w + (size_t)row * I;
    float s = 0.f, s2 = 0.f;
    for (int i = threadIdx.x; i < I; i += 256) { float v = wr[i]; s += v; s2 += v * v; }
#pragma unroll
    for (int off = 32; off > 0; off >>= 1) { s += __shfl_down(s, off); s2 += __shfl_down(s2, off); }
    __shared__ float sa[4], sb[4], smean, srstd;
    int wid = threadIdx.x >> 6;
    if ((threadIdx.x & 63) == 0) { sa[wid] = s; sb[wid] = s2; }
    __syncthreads();
    if (threadIdx.x == 0) {
        float ts = sa[0] + sa[1] + sa[2] + sa[3];
        float ts2 = sb[0] + sb[1] + sb[2] + sb[3];
        float mean = ts / (float)I;
        float var = ts2 / (float)I - mean * mean;
        smean = mean; srstd = rsqrtf(var + EPSF);
    }
    __syncthreads();
    float mean = smean, r = srstd;
    u16* wo = wn + (size_t)row * I;
    for (int i = threadIdx.x; i < I; i += 256) wo[i] = f2bu((wr[i] - mean) * r);
}

// ---------------------------------------------------------------------------
// Fused transpose of x and ctx: f32 [b][R][C] -> bf16 [b][C][R], C=1024.
// grid (16, 16+12, NB): y<16 -> x (R=1024), y>=16 -> ctx (R=768).
// ---------------------------------------------------------------------------
__global__ __launch_bounds__(256) void transpose2(
    const float* __restrict__ x, const float* __restrict__ ctx,
    u16* __restrict__ xT, u16* __restrict__ cT) {
    __shared__ float tile[64][65];
    int yy = blockIdx.y;
    int mat = yy < 16 ? 0 : 1;
    int r0 = (mat == 0 ? yy : yy - 16) * 64;
    int R = mat == 0 ? EE : CCH;
    const float* in = mat == 0 ? x : ctx;
    u16* out = mat == 0 ? xT : cT;
    int c0 = blockIdx.x * 64, b = blockIdx.z;
    const float* ip = in + (size_t)b * R * 1024;
    u16* op = out + (size_t)b * R * 1024;
    int tid = threadIdx.x;
#pragma unroll
    for (int m = 0; m < 16; m++) {
        int id = tid + 256 * m; int r = id >> 6, c = id & 63;
        tile[r][c] = ip[(size_t)(r0 + r) * 1024 + c0 + c];
    }
    __syncthreads();
#pragma unroll
    for (int m = 0; m < 16; m++) {
        int id = tid + 256 * m; int rr = id >> 6, cc = id & 63;
        op[(size_t)(c0 + rr) * R + r0 + cc] = tile[cc][rr];
    }
}
// note: transpose2 writes bf16 via f2bu below (specialized in-loop)
// (implemented as a second pass to keep the tile in f32) -- see body above:
// we convert on store:
__global__ __launch_bounds__(256) void transpose2_f2b(
    const float* __restrict__ x, const float* __restrict__ ctx,
    u16* __restrict__ xT, u16* __restrict__ cT) {
    __shared__ float tile[64][65];
    int yy = blockIdx.y;
    int mat = yy < 16 ? 0 : 1;
    int r0 = (mat == 0 ? yy : yy - 16) * 64;
    int R = mat == 0 ? EE : CCH;
    const float* in = mat == 0 ? x : ctx;
    u16* out = mat == 0 ? xT : cT;
    int c0 = blockIdx.x * 64, b = blockIdx.z;
    const float* ip = in + (size_t)b * R * 1024;
    u16* op = out + (size_t)b * R * 1024;
    int tid = threadIdx.x;
#pragma unroll
    for (int m = 0; m < 16; m++) {
        int id = tid + 256 * m; int r = id >> 6, c = id & 63;
        tile[r][c] = ip[(size_t)(r0 + r) * 1024 + c0 + c];
    }
    __syncthreads();
#pragma unroll
    for (int m = 0; m < 16; m++) {
        int id = tid + 256 * m; int rr = id >> 6, cc = id & 63;
        op[(size_t)(c0 + rr) * R + r0 + cc] = f2bu(tile[cc][rr]);
    }
}

// ---------------------------------------------------------------------------
// MFMA projection core: 128x64 tile (M=O rows, N=L cols), 4 waves, each wave
// a 64x32 quadrant (4x2 16x16x32 frags). +bias, mask over l, optional f32
// residual; bf16 or f32 out.
// ---------------------------------------------------------------------------
__device__ __forceinline__ void proj_core(
    const u16* __restrict__ A, const u16* __restrict__ BT,
    const float* __restrict__ bias, const int* __restrict__ mask,
    const float* __restrict__ resid, u16* __restrict__ outB, float* __restrict__ outF,
    int O, int I, int L, int o0, int l0, int b,
    u16 (*at)[72], u16 (*bt)[72]) {
    int tid = threadIdx.x;
    int w = tid >> 6, lane = tid & 63, quad = lane >> 4, l16 = lane & 15;
    int wm = w & 1, wn = w >> 1;          // M-half (64), N-half (32)
    const u16* Bp = BT + (size_t)b * L * I;

    f32x4 acc[4][2] = {};
    for (int k0 = 0; k0 < I; k0 += 64) {
        __syncthreads();
#pragma unroll
        for (int m = 0; m < 4; m++) {       // A tile: 128 x 64
            int id = tid + 256 * m; int r = id >> 3, c = (id & 7) * 8;
            *(u16x8*)&at[r][c] = *(const u16x8*)&A[(size_t)(o0 + r) * I + k0 + c];
        }
#pragma unroll
        for (int m = 0; m < 2; m++) {       // B tile: 64 x 64
            int id = tid + 256 * m; int r = id >> 3, c = (id & 7) * 8;
            *(u16x8*)&bt[r][c] = *(const u16x8*)&Bp[(size_t)(l0 + r) * I + k0 + c];
        }
        __syncthreads();
#pragma unroll
        for (int ks = 0; ks < 64; ks += 32) {
            short8 af[4], bf[2];
#pragma unroll
            for (int i = 0; i < 4; i++)
                af[i] = *(const short8*)&at[wm * 64 + i * 16 + l16][ks + quad * 8];
#pragma unroll
            for (int j = 0; j < 2; j++)
                bf[j] = *(const short8*)&bt[wn * 32 + j * 16 + l16][ks + quad * 8];
#pragma unroll
            for (int mt = 0; mt < 4; mt++)
#pragma unroll
                for (int nt = 0; nt < 2; nt++)
                    acc[mt][nt] = MFMA16(af[mt], bf[nt], acc[mt][nt]);
        }
    }
    const int* mrow = mask + (size_t)b * L;
#pragma unroll
    for (int nt = 0; nt < 2; nt++) {
        int l = l0 + wn * 32 + nt * 16 + l16;
        int mval = mrow[l];
#pragma unroll
        for (int mt = 0; mt < 4; mt++) {
#pragma unroll
            for (int reg = 0; reg < 4; reg++) {
                int o = o0 + wm * 64 + mt * 16 + quad * 4 + reg;
                float v = mval ? (acc[mt][nt][reg] + bias[o]) : 0.f;
                size_t off = ((size_t)b * O + o) * L + l;
                if (resid) v += resid[off];
                if (outF) outF[off] = v; else outB[off] = f2bu(v);
            }
        }
    }
}

// Fused q/k/v projections: grid (16, 24, NB); blockIdx.y>>3 selects matrix.
__global__ __launch_bounds__(256) void proj_qkv(
    const u16* __restrict__ wq, const u16* __restrict__ wk, const u16* __restrict__ wv,
    const u16* __restrict__ xT, const u16* __restrict__ cT,
    const float* __restrict__ qb, const float* __restrict__ kb, const float* __restrict__ vbi,
    const int* __restrict__ mask_t, const int* __restrict__ mask_c,
    u16* __restrict__ yq, u16* __restrict__ yk, u16* __restrict__ yv) {
    __shared__ u16 at[128][72];
    __shared__ u16 bt[64][72];
    int mat = blockIdx.y >> 3;
    int o0 = (blockIdx.y & 7) * 128;
    int l0 = blockIdx.x * 64;
    const u16* A = mat == 0 ? wq : (mat == 1 ? wk : wv);
    const u16* BT = mat == 0 ? xT : cT;
    const float* bias = mat == 0 ? qb : (mat == 1 ? kb : vbi);
    const int* mask = mat == 0 ? mask_t : mask_c;
    u16* out = mat == 0 ? yq : (mat == 1 ? yk : yv);
    int I = mat == 0 ? EE : CCH;
    proj_core(A, BT, bias, mask, nullptr, out, nullptr, EE, I, 1024, o0, l0,
              blockIdx.z, at, bt);
}

// Output projection (+mask, +f32 residual) -> f32. grid (16, 8, NB).
__global__ __launch_bounds__(256) void proj_o(
    const u16* __restrict__ won, const u16* __restrict__ aT,
    const float* __restrict__ obi, const int* __restrict__ mask,
    const float* __restrict__ x, float* __restrict__ out) {
    __shared__ u16 at[128][72];
    __shared__ u16 bt[64][72];
    proj_core(won, aT, obi, mask, x, nullptr, out, EE, EE, TT,
              blockIdx.y * 128, blockIdx.x * 64, blockIdx.z, at, bt);
}

// ---------------------------------------------------------------------------
// Fused per-head LayerNorm for q (scale=QSCALE) and k (scale=1):
// bf16 [b][E][L] -> bf16 [bh][l][d].  grid (512): first 256 blocks q, rest k.
// ---------------------------------------------------------------------------
__global__ __launch_bounds__(256) void ln_qk(
    const u16* __restrict__ yq, const u16* __restrict__ yk,
    const float* __restrict__ gq, const float* __restrict__ bq,
    const float* __restrict__ gk, const float* __restrict__ bk,
    u16* __restrict__ qT, u16* __restrict__ kT) {
    int part = blockIdx.x >> 8;
    const u16* y = part == 0 ? yq : yk;
    const float* g = part == 0 ? gq : gk;
    const float* be = part == 0 ? bq : bk;
    u16* outT = part == 0 ? qT : kT;
    float scale = part == 0 ? QSCALE : 1.0f;
    int idx = (blockIdx.x & 255) * 256 + threadIdx.x;
    int l = idx & 1023; int bh = idx >> 10;
    size_t base = ((size_t)bh * 64) * 1024 + l;
    float v[DHH]; float s = 0.f;
#pragma unroll
    for (int d = 0; d < DHH; d++) { v[d] = bu2f(y[base + (size_t)d * 1024]); s += v[d]; }
    float mean = s * (1.f / DHH);
    float s2 = 0.f;
#pragma unroll
    for (int d = 0; d < DHH; d++) { float dv = v[d] - mean; s2 += dv * dv; }
    float r = rsqrtf(s2 * (1.f / DHH) + EPSF);
    u16* o = outT + ((size_t)bh * 1024 + l) * DHH;
#pragma unroll
    for (int d = 0; d < DHH; d++)
        o[d] = f2bu(((v[d] - mean) * r * g[d] + be[d]) * scale);
}

// ---------------------------------------------------------------------------
// V LayerNorm + fold mask_ctx[s]/l_s into V (in place, layout [b][E][S]).
// ---------------------------------------------------------------------------
__global__ __launch_bounds__(256) void ln_v_scale(u16* __restrict__ y,
                                                  const float* __restrict__ g,
                                                  const float* __restrict__ be,
                                                  const int* __restrict__ mask_ctx,
                                                  const float* __restrict__ lrow, int L) {
    int idx = blockIdx.x * 256 + threadIdx.x;
    int l = idx % L; int bh = idx / L; int b = bh / NH;
    size_t base = ((size_t)bh * 64) * L + l;
    float v[DHH]; float s = 0.f;
#pragma unroll
    for (int d = 0; d < DHH; d++) { v[d] = bu2f(y[base + (size_t)d * L]); s += v[d]; }
    float mean = s * (1.f / DHH);
    float s2 = 0.f;
#pragma unroll
    for (int d = 0; d < DHH; d++) { float dv = v[d] - mean; s2 += dv * dv; }
    float r = rsqrtf(s2 * (1.f / DHH) + EPSF);
    float lv = lrow[(size_t)bh * L + l];
    float wsc = (mask_ctx[(size_t)b * L + l] != 0 && lv > 0.f) ? (1.f / lv) : 0.f;
#pragma unroll
    for (int d = 0; d < DHH; d++)
        y[base + (size_t)d * L] = f2bu(((v[d] - mean) * r * g[d] + be[d]) * wsc);
}

// ---------------------------------------------------------------------------
// Pass A: l_s = sum_t mask[t] * exp2(q'.k)  (q pre-scaled by log2e/256).
// grid (SS/64, NH, NB), 256 thr.
// ---------------------------------------------------------------------------
__global__ __launch_bounds__(256) void attn_stats_mfma(
    const u16* __restrict__ qT, const u16* __restrict__ kT,
    const int* __restrict__ mask, float* __restrict__ lrow) {
    __shared__ u16 kt[64][72];   // [s][d]
    __shared__ u16 qt[64][72];   // [t][d]
    __shared__ float lp[4][64];
    int tid = threadIdx.x;
    int w = tid >> 6, lane = tid & 63, quad = lane >> 4, l16 = lane & 15;
    int s0 = blockIdx.x * 64, h = blockIdx.y, b = blockIdx.z;
    int head = b * NH + h;
    const u16* kp = kT + (size_t)head * SS * DHH;
    const u16* qp = qT + (size_t)head * TT * DHH;
    const int* mk = mask + (size_t)b * TT;
#pragma unroll
    for (int m = 0; m < 2; m++) {
        int id = tid + 256 * m; int r = id >> 3, c = (id & 7) * 8;
        *(u16x8*)&kt[r][c] = *(const u16x8*)&kp[(size_t)(s0 + r) * DHH + c];
    }
    float rl[4][4] = {};
    for (int t0 = 0; t0 < TT; t0 += 64) {
        __syncthreads();
#pragma unroll
        for (int m = 0; m < 2; m++) {
            int id = tid + 256 * m; int r = id >> 3, c = (id & 7) * 8;
            *(u16x8*)&qt[r][c] = *(const u16x8*)&qp[(size_t)(t0 + r) * DHH + c];
        }
        __syncthreads();
        int mval = mk[t0 + w * 16 + l16];
        f32x4 acc[4] = {};
#pragma unroll
        for (int ks = 0; ks < 64; ks += 32) {
            short8 bf = *(const short8*)&qt[w * 16 + l16][ks + quad * 8];
#pragma unroll
            for (int mt = 0; mt < 4; mt++) {
                short8 af = *(const short8*)&kt[mt * 16 + l16][ks + quad * 8];
                acc[mt] = MFMA16(af, bf, acc[mt]);
            }
        }
        if (mval) {
#pragma unroll
            for (int mt = 0; mt < 4; mt++)
#pragma unroll
                for (int reg = 0; reg < 4; reg++)
                    rl[mt][reg] += EXP2(acc[mt][reg]);
        }
    }
#pragma unroll
    for (int mt = 0; mt < 4; mt++) {
#pragma unroll
        for (int reg = 0; reg < 4; reg++) {
            float v = rl[mt][reg];
            v += __shfl_xor(v, 1); v += __shfl_xor(v, 2);
            v += __shfl_xor(v, 4); v += __shfl_xor(v, 8);
            if (l16 == 0) lp[w][mt * 16 + quad * 4 + reg] = v;
        }
    }
    __syncthreads();
    if (tid < 64)
        lrow[(size_t)head * SS + s0 + tid] = lp[0][tid] + lp[1][tid] + lp[2][tid] + lp[3][tid];
}

// ---------------------------------------------------------------------------
// Pass B: out[t][e] = sum_s V'[d][s] * Praw[s][t], Praw = mask[t]*exp2(q'.k)
// (V' already carries mask_ctx/l). Score MFMA order is bit-identical to pass A.
// Output is LDS-transposed and written directly as aT [b][t][e=h*64+d].
// grid (TT/64, NH, NB)
// ---------------------------------------------------------------------------
__global__ __launch_bounds__(256) void attn_pv_mfma(
    const u16* __restrict__ qT, const u16* __restrict__ kT, const u16* __restrict__ vs,
    const int* __restrict__ mask, u16* __restrict__ aT) {
    __shared__ u16 qt[64][72];   // [t][d]
    __shared__ u16 kt[64][72];   // [s][d]
    __shared__ u16 vt[64][72];   // [d][s]
    __shared__ u16 pt[64][72];   // [t][s] (B-operand for PV); reused for out tile
    int tid = threadIdx.x;
    int w = tid >> 6, lane = tid & 63, quad = lane >> 4, l16 = lane & 15;
    int t0 = blockIdx.x * 64, h = blockIdx.y, b = blockIdx.z;
    int head = b * NH + h;
    const u16* qp = qT + (size_t)head * TT * DHH;
    const u16* kp = kT + (size_t)head * SS * DHH;
    const u16* vp = vs + ((size_t)head * DHH) * SS;
#pragma unroll
    for (int m = 0; m < 2; m++) {
        int id = tid + 256 * m; int r = id >> 3, c = (id & 7) * 8;
        *(u16x8*)&qt[r][c] = *(const u16x8*)&qp[(size_t)(t0 + r) * DHH + c];
    }
    int mkv = mask[(size_t)b * TT + t0 + w * 16 + l16];

    f32x4 oacc[4] = {};
    for (int s0 = 0; s0 < SS; s0 += 64) {
        __syncthreads();
#pragma unroll
        for (int m = 0; m < 2; m++) {
            int id = tid + 256 * m; int r = id >> 3, c = (id & 7) * 8;
            *(u16x8*)&kt[r][c] = *(const u16x8*)&kp[(size_t)(s0 + r) * DHH + c];
            *(u16x8*)&vt[r][c] = *(const u16x8*)&vp[(size_t)r * SS + s0 + c];
        }
        __syncthreads();
        f32x4 acc[4] = {};
#pragma unroll
        for (int ks = 0; ks < 64; ks += 32) {
            short8 bf = *(const short8*)&qt[w * 16 + l16][ks + quad * 8];
#pragma unroll
            for (int mt = 0; mt < 4; mt++) {
                short8 af = *(const short8*)&kt[mt * 16 + l16][ks + quad * 8];
                acc[mt] = MFMA16(af, bf, acc[mt]);
            }
        }
#pragma unroll
        for (int mt = 0; mt < 4; mt++) {
#pragma unroll
            for (int reg = 0; reg < 4; reg++) {
                int sl = mt * 16 + quad * 4 + reg;
                float p = mkv ? EXP2(acc[mt][reg]) : 0.f;
                pt[w * 16 + l16][sl] = f2bu(p);
            }
        }
        __syncthreads();
#pragma unroll
        for (int ks = 0; ks < 64; ks += 32) {
            short8 bf = *(const short8*)&pt[w * 16 + l16][ks + quad * 8];
#pragma unroll
            for (int mt = 0; mt < 4; mt++) {
                short8 af = *(const short8*)&vt[mt * 16 + l16][ks + quad * 8];
                oacc[mt] = MFMA16(af, bf, oacc[mt]);
            }
        }
    }
    __syncthreads();
    int tl = w * 16 + l16;
#pragma unroll
    for (int mt = 0; mt < 4; mt++) {
        u16x4 pk;
#pragma unroll
        for (int reg = 0; reg < 4; reg++) pk[reg] = f2bu(oacc[mt][reg]);
        *(u16x4*)&pt[tl][mt * 16 + quad * 4] = pk;
    }
    __syncthreads();
#pragma unroll
    for (int i = 0; i < 2; i++) {
        int id = tid * 2 + i;
        int r = id >> 3, c = (id & 7) * 8;
        *(u16x8*)&aT[((size_t)b * TT + t0 + r) * EE + h * 64 + c] =
            *(const u16x8*)&pt[r][c];
    }
}

// ---------------------------------------------------------------------------
extern "C" void kernel_launch(void* const* d_in, const int* in_sizes, int n_in,
                              void* d_out, int out_size, void* d_ws, size_t ws_size,
                              hipStream_t stream) {
    const float* x        = (const float*)d_in[0];
    const float* ctx      = (const float*)d_in[1];
    const int*   mask     = (const int*)d_in[2];
    const int*   mask_ctx = (const int*)d_in[3];
    const float* qw  = (const float*)d_in[4];
    const float* qbi = (const float*)d_in[5];
    const float* kw  = (const float*)d_in[6];
    const float* kbi = (const float*)d_in[7];
    const float* vw  = (const float*)d_in[8];
    const float* vbi = (const float*)d_in[9];
    const float* ow  = (const float*)d_in[10];
    const float* obi = (const float*)d_in[11];
    const float* gq = (const float*)d_in[12];
    const float* bq = (const float*)d_in[13];
    const float* gk = (const float*)d_in[14];
    const float* bk = (const float*)d_in[15];
    const float* gv = (const float*)d_in[16];
    const float* bv = (const float*)d_in[17];

    // workspace carve (~61.5 MB)
    u16* p = (u16*)d_ws;
    u16* wqn = p; p += (size_t)EE * EE;
    u16* wkn = p; p += (size_t)EE * CCH;
    u16* wvn = p; p += (size_t)EE * CCH;
    u16* won = p; p += (size_t)EE * EE;
    u16* xT  = p; p += (size_t)NB * TT * EE;     // [b][t][e]
    u16* cT  = p; p += (size_t)NB * SS * CCH;    // [b][s][c]
    u16* yq  = p; p += (size_t)NB * EE * TT;     // q proj out; reused as aT later
    u16* yk  = p; p += (size_t)NB * EE * SS;     // k proj out
    u16* yv  = p; p += (size_t)NB * EE * SS;     // v proj out, LN+scale in place
    u16* qT  = p; p += (size_t)NB * NH * TT * DHH;  // [bh][t][d], pre-scaled
    u16* kT  = p; p += (size_t)NB * NH * SS * DHH;  // [bh][s][d]
    float* lrow = (float*)p;                     // [bh][s]
    u16* aT = yq;                                // attn out [b][t][e] (yq dead)

    // 1) weight standardization (all 4 in one dispatch)
    ws_norm4<<<dim3(1024, 4), 256, 0, stream>>>(qw, kw, vw, ow, wqn, wkn, wvn, won);

    // 2) fused transpose of x and ctx to [l][i] bf16
    transpose2_f2b<<<dim3(16, 28, NB), 256, 0, stream>>>(x, ctx, xT, cT);

    // 3) fused q/k/v projections: 128x64 tiles, 1536 blocks (~5 blocks/CU)
    proj_qkv<<<dim3(16, 24, NB), 256, 0, stream>>>(
        wqn, wkn, wvn, xT, cT, qbi, kbi, vbi, mask, mask_ctx, yq, yk, yv);

    // 4) fused per-head LN for q (folded exp2 scale) and k -> [bh][l][d]
    ln_qk<<<512, 256, 0, stream>>>(yq, yk, gq, bq, gk, bk, qT, kT);

    // 5) softmax denominators, then fold mask_ctx/l into V's LN
    attn_stats_mfma<<<dim3(SS / 64, NH, NB), 256, 0, stream>>>(qT, kT, mask, lrow);
    ln_v_scale<<<(NB * NH * SS) / 256, 256, 0, stream>>>(yv, gv, bv, mask_ctx, lrow, SS);

    // 6) PV pass -> aT [b][t][e] directly
    attn_pv_mfma<<<dim3(TT / 64, NH, NB), 256, 0, stream>>>(qT, kT, yv, mask, aT);

    // 7) o-proj (+mask +f32 residual) -> f32 d_out, 128x64 tiles, 512 blocks
    proj_o<<<dim3(16, 8, NB), 256, 0, stream>>>(won, aT, obi, mask, x, (float*)d_out);
}

// Round 6
// 252.000 us; speedup vs baseline: 10.0237x; 1.0925x over previous
//
#include <hip/hip_runtime.h>

// Problem constants (B=4, T=S=1024, E=1024, CTX=768, H=16, DH=64)
#define NB 4
#define TT 1024
#define SS 1024
#define EE 1024
#define CCH 768
#define NH 16
#define DHH 64
#define EPSF 1e-5f
// SCALE = 1024 // (16**0.5) = 256.  Fold 1/256 * log2(e) into q so that
// exp(score/256) == exp2(q'.k) with a single v_exp_f32.
#define QSCALE (1.4426950408889634f / 256.0f)

typedef unsigned short u16;
typedef __attribute__((ext_vector_type(8))) short short8;       // MFMA A/B frag
typedef __attribute__((ext_vector_type(8))) unsigned short u16x8;
typedef __attribute__((ext_vector_type(4))) unsigned short u16x4;
typedef __attribute__((ext_vector_type(4))) float f32x4;        // MFMA C/D frag

__device__ __forceinline__ u16 f2bu(float f) {
    union { float f; unsigned u; } x; x.f = f;
    unsigned r = x.u + 0x7fffu + ((x.u >> 16) & 1u);
    return (u16)(r >> 16);
}
__device__ __forceinline__ float bu2f(u16 u) {
    union { unsigned u; float f; } x; x.u = ((unsigned)u) << 16; return x.f;
}

#if __has_builtin(__builtin_amdgcn_exp2f)
#define EXP2(x) __builtin_amdgcn_exp2f(x)
#else
#define EXP2(x) exp2f(x)
#endif

#define MFMA16(a, b, c) __builtin_amdgcn_mfma_f32_16x16x32_bf16((a), (b), (c), 0, 0, 0)

// ---------------------------------------------------------------------------
// Weight standardization, all 4 matrices in one dispatch.
// grid (1024, 4): one block per row, blockIdx.y selects the matrix.
// ---------------------------------------------------------------------------
__global__ __launch_bounds__(256) void ws_norm4(
    const float* __restrict__ qw, const float* __restrict__ kw,
    const float* __restrict__ vw, const float* __restrict__ ow,
    u16* __restrict__ wqn, u16* __restrict__ wkn,
    u16* __restrict__ wvn, u16* __restrict__ won) {
    int mat = blockIdx.y;
    const float* w = mat == 0 ? qw : (mat == 1 ? kw : (mat == 2 ? vw : ow));
    u16* wn = mat == 0 ? wqn : (mat == 1 ? wkn : (mat == 2 ? wvn : won));
    int I = (mat == 1 || mat == 2) ? CCH : EE;
    int row = blockIdx.x;
    const float* wr = w + (size_t)row * I;
    float s = 0.f, s2 = 0.f;
    for (int i = threadIdx.x; i < I; i += 256) { float v = wr[i]; s += v; s2 += v * v; }
#pragma unroll
    for (int off = 32; off > 0; off >>= 1) { s += __shfl_down(s, off); s2 += __shfl_down(s2, off); }
    __shared__ float sa[4], sb[4], smean, srstd;
    int wid = threadIdx.x >> 6;
    if ((threadIdx.x & 63) == 0) { sa[wid] = s; sb[wid] = s2; }
    __syncthreads();
    if (threadIdx.x == 0) {
        float ts = sa[0] + sa[1] + sa[2] + sa[3];
        float ts2 = sb[0] + sb[1] + sb[2] + sb[3];
        float mean = ts / (float)I;
        float var = ts2 / (float)I - mean * mean;
        smean = mean; srstd = rsqrtf(var + EPSF);
    }
    __syncthreads();
    float mean = smean, r = srstd;
    u16* wo = wn + (size_t)row * I;
    for (int i = threadIdx.x; i < I; i += 256) wo[i] = f2bu((wr[i] - mean) * r);
}

// ---------------------------------------------------------------------------
// Fused transpose of x and ctx: f32 [b][R][1024] -> bf16 [b][1024][R].
// grid (16, 16+12, NB): y<16 -> x (R=1024), y>=16 -> ctx (R=768).
// ---------------------------------------------------------------------------
__global__ __launch_bounds__(256) void transpose2_f2b(
    const float* __restrict__ x, const float* __restrict__ ctx,
    u16* __restrict__ xT, u16* __restrict__ cT) {
    __shared__ float tile[64][65];
    int yy = blockIdx.y;
    int mat = yy < 16 ? 0 : 1;
    int r0 = (mat == 0 ? yy : yy - 16) * 64;
    int R = mat == 0 ? EE : CCH;
    const float* in = mat == 0 ? x : ctx;
    u16* out = mat == 0 ? xT : cT;
    int c0 = blockIdx.x * 64, b = blockIdx.z;
    const float* ip = in + (size_t)b * R * 1024;
    u16* op = out + (size_t)b * R * 1024;
    int tid = threadIdx.x;
#pragma unroll
    for (int m = 0; m < 16; m++) {
        int id = tid + 256 * m; int r = id >> 6, c = id & 63;
        tile[r][c] = ip[(size_t)(r0 + r) * 1024 + c0 + c];
    }
    __syncthreads();
#pragma unroll
    for (int m = 0; m < 16; m++) {
        int id = tid + 256 * m; int rr = id >> 6, cc = id & 63;
        op[(size_t)(c0 + rr) * R + r0 + cc] = f2bu(tile[cc][rr]);
    }
}

// ---------------------------------------------------------------------------
// GEMM core: 128x64 tile (M=O rows, N=L cols), 4 waves, each a 64x32 quadrant
// (4x2 16x16x32 frags). Register double-buffer: next K-tile's global chunks
// are loaded into VGPRs during the current tile's MFMA.
// ---------------------------------------------------------------------------
__device__ __forceinline__ void gemm_core(
    const u16* __restrict__ A, const u16* __restrict__ Bp, int I,
    int o0, int l0, u16 (*at)[72], u16 (*bt)[72], f32x4 (&acc)[4][2]) {
    int tid = threadIdx.x;
    int w = tid >> 6, lane = tid & 63, quad = lane >> 4, l16 = lane & 15;
    int wm = w & 1, wn = w >> 1;
    u16x8 ra[4], rb[2];
#pragma unroll
    for (int m = 0; m < 4; m++) {
        int id = tid + 256 * m; int r = id >> 3, c = (id & 7) * 8;
        ra[m] = *(const u16x8*)&A[(size_t)(o0 + r) * I + c];
    }
#pragma unroll
    for (int m = 0; m < 2; m++) {
        int id = tid + 256 * m; int r = id >> 3, c = (id & 7) * 8;
        rb[m] = *(const u16x8*)&Bp[(size_t)(l0 + r) * I + c];
    }
    for (int k0 = 0; k0 < I; k0 += 64) {
        __syncthreads();
#pragma unroll
        for (int m = 0; m < 4; m++) {
            int id = tid + 256 * m; int r = id >> 3, c = (id & 7) * 8;
            *(u16x8*)&at[r][c] = ra[m];
        }
#pragma unroll
        for (int m = 0; m < 2; m++) {
            int id = tid + 256 * m; int r = id >> 3, c = (id & 7) * 8;
            *(u16x8*)&bt[r][c] = rb[m];
        }
        __syncthreads();
        int k1 = k0 + 64;
        if (k1 < I) {
#pragma unroll
            for (int m = 0; m < 4; m++) {
                int id = tid + 256 * m; int r = id >> 3, c = (id & 7) * 8;
                ra[m] = *(const u16x8*)&A[(size_t)(o0 + r) * I + k1 + c];
            }
#pragma unroll
            for (int m = 0; m < 2; m++) {
                int id = tid + 256 * m; int r = id >> 3, c = (id & 7) * 8;
                rb[m] = *(const u16x8*)&Bp[(size_t)(l0 + r) * I + k1 + c];
            }
        }
#pragma unroll
        for (int ks = 0; ks < 64; ks += 32) {
            short8 af[4], bf[2];
#pragma unroll
            for (int i = 0; i < 4; i++)
                af[i] = *(const short8*)&at[wm * 64 + i * 16 + l16][ks + quad * 8];
#pragma unroll
            for (int j = 0; j < 2; j++)
                bf[j] = *(const short8*)&bt[wn * 32 + j * 16 + l16][ks + quad * 8];
#pragma unroll
            for (int mt = 0; mt < 4; mt++)
#pragma unroll
                for (int nt = 0; nt < 2; nt++)
                    acc[mt][nt] = MFMA16(af[mt], bf[nt], acc[mt][nt]);
        }
    }
}

// ---------------------------------------------------------------------------
// Fused q/k/v projections + per-head LayerNorm epilogue (q,k).
// grid (16, 24, NB); blockIdx.y>>3 selects matrix. A 128-row o-tile = 2 heads;
// for fixed l one wave holds all 64 d values (16 local + shfl_xor 16/32).
// q,k -> qT/kT [bh][l][d] (q pre-scaled by QSCALE); v -> yv [b][E][S] masked.
// ---------------------------------------------------------------------------
__global__ __launch_bounds__(256) void proj_qkv(
    const u16* __restrict__ wq, const u16* __restrict__ wk, const u16* __restrict__ wv,
    const u16* __restrict__ xT, const u16* __restrict__ cT,
    const float* __restrict__ qb, const float* __restrict__ kb, const float* __restrict__ vbi,
    const int* __restrict__ mask_t, const int* __restrict__ mask_c,
    const float* __restrict__ gq, const float* __restrict__ bq,
    const float* __restrict__ gk, const float* __restrict__ bk,
    u16* __restrict__ qT, u16* __restrict__ kT, u16* __restrict__ yv) {
    __shared__ u16 at[128][72];
    __shared__ u16 bt[64][72];
    __shared__ float sg[64], sbe[64], sbias[128];
    int tid = threadIdx.x;
    int w = tid >> 6, lane = tid & 63, quad = lane >> 4, l16 = lane & 15;
    int wm = w & 1, wn = w >> 1;
    int mat = blockIdx.y >> 3;
    int o0 = (blockIdx.y & 7) * 128;
    int l0 = blockIdx.x * 64;
    int b = blockIdx.z;
    const u16* A = mat == 0 ? wq : (mat == 1 ? wk : wv);
    const u16* BT = mat == 0 ? xT : cT;
    const float* bias = mat == 0 ? qb : (mat == 1 ? kb : vbi);
    const int* maskp = mat == 0 ? mask_t : mask_c;
    int I = mat == 0 ? EE : CCH;
    if (mat < 2 && tid < 64) {
        sg[tid] = (mat == 0 ? gq : gk)[tid];
        sbe[tid] = (mat == 0 ? bq : bk)[tid];
    }
    if (tid < 128) sbias[tid] = bias[o0 + tid];

    f32x4 acc[4][2] = {};
    gemm_core(A, BT + (size_t)b * 1024 * I, I, o0, l0, at, bt, acc);

    const int* mrow = maskp + (size_t)b * 1024;
    if (mat < 2) {
        u16* outT = mat == 0 ? qT : kT;
        float scale = mat == 0 ? QSCALE : 1.0f;
        int h = (o0 >> 6) + wm;            // head within batch
        int bh = b * NH + h;
#pragma unroll
        for (int nt = 0; nt < 2; nt++) {
            int l = l0 + wn * 32 + nt * 16 + l16;
            int mval = mrow[l];
            float vbuf[16];
            float s = 0.f;
#pragma unroll
            for (int mt = 0; mt < 4; mt++)
#pragma unroll
                for (int reg = 0; reg < 4; reg++) {
                    float v = mval ? (acc[mt][nt][reg] + sbias[wm * 64 + mt * 16 + quad * 4 + reg]) : 0.f;
                    vbuf[mt * 4 + reg] = v; s += v;
                }
            s += __shfl_xor(s, 16); s += __shfl_xor(s, 32);
            float mean = s * (1.f / 64);
            float s2 = 0.f;
#pragma unroll
            for (int i = 0; i < 16; i++) { float dv = vbuf[i] - mean; s2 += dv * dv; }
            s2 += __shfl_xor(s2, 16); s2 += __shfl_xor(s2, 32);
            float r = rsqrtf(s2 * (1.f / 64) + EPSF);
            u16* op = outT + ((size_t)bh * 1024 + l) * 64;
#pragma unroll
            for (int mt = 0; mt < 4; mt++) {
                u16x4 pk;
#pragma unroll
                for (int reg = 0; reg < 4; reg++) {
                    int d = mt * 16 + quad * 4 + reg;
                    pk[reg] = f2bu(((vbuf[mt * 4 + reg] - mean) * r * sg[d] + sbe[d]) * scale);
                }
                *(u16x4*)&op[mt * 16 + quad * 4] = pk;
            }
        }
    } else {
#pragma unroll
        for (int nt = 0; nt < 2; nt++) {
            int l = l0 + wn * 32 + nt * 16 + l16;
            int mval = mrow[l];
#pragma unroll
            for (int mt = 0; mt < 4; mt++)
#pragma unroll
                for (int reg = 0; reg < 4; reg++) {
                    int o = o0 + wm * 64 + mt * 16 + quad * 4 + reg;
                    float v = mval ? (acc[mt][nt][reg] + sbias[wm * 64 + mt * 16 + quad * 4 + reg]) : 0.f;
                    yv[((size_t)b * EE + o) * 1024 + l] = f2bu(v);
                }
        }
    }
}

// ---------------------------------------------------------------------------
// Output projection (+mask, +f32 residual) -> f32. grid (16, 8, NB).
// ---------------------------------------------------------------------------
__global__ __launch_bounds__(256) void proj_o(
    const u16* __restrict__ won, const u16* __restrict__ aT,
    const float* __restrict__ obi, const int* __restrict__ mask,
    const float* __restrict__ x, float* __restrict__ out) {
    __shared__ u16 at[128][72];
    __shared__ u16 bt[64][72];
    __shared__ float sbias[128];
    int tid = threadIdx.x;
    int w = tid >> 6, lane = tid & 63, quad = lane >> 4, l16 = lane & 15;
    int wm = w & 1, wn = w >> 1;
    int o0 = blockIdx.y * 128, l0 = blockIdx.x * 64, b = blockIdx.z;
    if (tid < 128) sbias[tid] = obi[o0 + tid];
    f32x4 acc[4][2] = {};
    gemm_core(won, aT + (size_t)b * TT * EE, EE, o0, l0, at, bt, acc);
    const int* mrow = mask + (size_t)b * TT;
#pragma unroll
    for (int nt = 0; nt < 2; nt++) {
        int l = l0 + wn * 32 + nt * 16 + l16;
        int mval = mrow[l];
#pragma unroll
        for (int mt = 0; mt < 4; mt++)
#pragma unroll
            for (int reg = 0; reg < 4; reg++) {
                int o = o0 + wm * 64 + mt * 16 + quad * 4 + reg;
                float v = mval ? (acc[mt][nt][reg] + sbias[wm * 64 + mt * 16 + quad * 4 + reg]) : 0.f;
                size_t off = ((size_t)b * EE + o) * TT + l;
                out[off] = v + x[off];
            }
    }
}

// ---------------------------------------------------------------------------
// Pass A: l_s = sum_t mask[t]*exp2(q'.k), then fused V LayerNorm + fold of
// mask_ctx[s]/l_s into V (in place). grid (SS/64, NH, NB), 256 thr.
// ---------------------------------------------------------------------------
__global__ __launch_bounds__(256) void attn_stats_mfma(
    const u16* __restrict__ qT, const u16* __restrict__ kT,
    const int* __restrict__ mask, const int* __restrict__ mask_ctx,
    const float* __restrict__ gv, const float* __restrict__ bv,
    u16* __restrict__ yv) {
    __shared__ u16 kt[64][72];   // [s][d]
    __shared__ u16 qt[64][72];   // [t][d]
    __shared__ float lp[4][64];
    int tid = threadIdx.x;
    int w = tid >> 6, lane = tid & 63, quad = lane >> 4, l16 = lane & 15;
    int s0 = blockIdx.x * 64, h = blockIdx.y, b = blockIdx.z;
    int head = b * NH + h;
    const u16* kp = kT + (size_t)head * SS * DHH;
    const u16* qp = qT + (size_t)head * TT * DHH;
    const int* mk = mask + (size_t)b * TT;
#pragma unroll
    for (int m = 0; m < 2; m++) {
        int id = tid + 256 * m; int r = id >> 3, c = (id & 7) * 8;
        *(u16x8*)&kt[r][c] = *(const u16x8*)&kp[(size_t)(s0 + r) * DHH + c];
    }
    u16x8 rq[2];
#pragma unroll
    for (int m = 0; m < 2; m++) {
        int id = tid + 256 * m; int r = id >> 3, c = (id & 7) * 8;
        rq[m] = *(const u16x8*)&qp[(size_t)r * DHH + c];
    }
    float rl[4][4] = {};
    for (int t0 = 0; t0 < TT; t0 += 64) {
        __syncthreads();
#pragma unroll
        for (int m = 0; m < 2; m++) {
            int id = tid + 256 * m; int r = id >> 3, c = (id & 7) * 8;
            *(u16x8*)&qt[r][c] = rq[m];
        }
        __syncthreads();
        int t1 = t0 + 64;
        if (t1 < TT) {
#pragma unroll
            for (int m = 0; m < 2; m++) {
                int id = tid + 256 * m; int r = id >> 3, c = (id & 7) * 8;
                rq[m] = *(const u16x8*)&qp[(size_t)(t1 + r) * DHH + c];
            }
        }
        int mval = mk[t0 + w * 16 + l16];
        f32x4 acc[4] = {};
#pragma unroll
        for (int ks = 0; ks < 64; ks += 32) {
            short8 bf = *(const short8*)&qt[w * 16 + l16][ks + quad * 8];
#pragma unroll
            for (int mt = 0; mt < 4; mt++) {
                short8 af = *(const short8*)&kt[mt * 16 + l16][ks + quad * 8];
                acc[mt] = MFMA16(af, bf, acc[mt]);
            }
        }
        if (mval) {
#pragma unroll
            for (int mt = 0; mt < 4; mt++)
#pragma unroll
                for (int reg = 0; reg < 4; reg++)
                    rl[mt][reg] += EXP2(acc[mt][reg]);
        }
    }
#pragma unroll
    for (int mt = 0; mt < 4; mt++) {
#pragma unroll
        for (int reg = 0; reg < 4; reg++) {
            float v = rl[mt][reg];
            v += __shfl_xor(v, 1); v += __shfl_xor(v, 2);
            v += __shfl_xor(v, 4); v += __shfl_xor(v, 8);
            if (l16 == 0) lp[w][mt * 16 + quad * 4 + reg] = v;
        }
    }
    __syncthreads();
    // fused V LayerNorm + mask_ctx/l fold for s0..s0+63 (64 threads)
    if (tid < 64) {
        int s = s0 + tid;
        float lv = lp[0][tid] + lp[1][tid] + lp[2][tid] + lp[3][tid];
        int mc = mask_ctx[(size_t)b * SS + s];
        float wsc = (mc != 0 && lv > 0.f) ? (1.f / lv) : 0.f;
        u16* vcol = yv + ((size_t)b * EE + h * 64) * SS + s;
        float sm = 0.f, s2 = 0.f;
#pragma unroll
        for (int d = 0; d < DHH; d++) {
            float v = bu2f(vcol[(size_t)d * SS]);
            sm += v; s2 += v * v;
        }
        float mean = sm * (1.f / DHH);
        float var = s2 * (1.f / DHH) - mean * mean;
        float r = rsqrtf(var + EPSF);
#pragma unroll
        for (int d = 0; d < DHH; d++) {
            float v = bu2f(vcol[(size_t)d * SS]);
            vcol[(size_t)d * SS] = f2bu(((v - mean) * r * gv[d] + bv[d]) * wsc);
        }
    }
}

// ---------------------------------------------------------------------------
// Pass B: out[t][e] = sum_s V'[d][s] * Praw[s][t], Praw = mask[t]*exp2(q'.k)
// (V' already carries mask_ctx/l). Score MFMA order is bit-identical to pass A.
// Output is LDS-transposed and written directly as aT [b][t][e=h*64+d].
// grid (TT/64, NH, NB)
// ---------------------------------------------------------------------------
__global__ __launch_bounds__(256) void attn_pv_mfma(
    const u16* __restrict__ qT, const u16* __restrict__ kT, const u16* __restrict__ vs,
    const int* __restrict__ mask, u16* __restrict__ aT) {
    __shared__ u16 qt[64][72];   // [t][d]
    __shared__ u16 kt[64][72];   // [s][d]
    __shared__ u16 vt[64][72];   // [d][s]
    __shared__ u16 pt[64][72];   // [t][s] (B-operand for PV); reused for out tile
    int tid = threadIdx.x;
    int w = tid >> 6, lane = tid & 63, quad = lane >> 4, l16 = lane & 15;
    int t0 = blockIdx.x * 64, h = blockIdx.y, b = blockIdx.z;
    int head = b * NH + h;
    const u16* qp = qT + (size_t)head * TT * DHH;
    const u16* kp = kT + (size_t)head * SS * DHH;
    const u16* vp = vs + ((size_t)head * DHH) * SS;
#pragma unroll
    for (int m = 0; m < 2; m++) {
        int id = tid + 256 * m; int r = id >> 3, c = (id & 7) * 8;
        *(u16x8*)&qt[r][c] = *(const u16x8*)&qp[(size_t)(t0 + r) * DHH + c];
    }
    u16x8 rk[2], rv[2];
#pragma unroll
    for (int m = 0; m < 2; m++) {
        int id = tid + 256 * m; int r = id >> 3, c = (id & 7) * 8;
        rk[m] = *(const u16x8*)&kp[(size_t)r * DHH + c];
        rv[m] = *(const u16x8*)&vp[(size_t)r * SS + c];
    }
    int mkv = mask[(size_t)b * TT + t0 + w * 16 + l16];
    int tl = w * 16 + l16;

    f32x4 oacc[4] = {};
    for (int s0 = 0; s0 < SS; s0 += 64) {
        __syncthreads();
#pragma unroll
        for (int m = 0; m < 2; m++) {
            int id = tid + 256 * m; int r = id >> 3, c = (id & 7) * 8;
            *(u16x8*)&kt[r][c] = rk[m];
            *(u16x8*)&vt[r][c] = rv[m];
        }
        __syncthreads();
        int s1 = s0 + 64;
        if (s1 < SS) {
#pragma unroll
            for (int m = 0; m < 2; m++) {
                int id = tid + 256 * m; int r = id >> 3, c = (id & 7) * 8;
                rk[m] = *(const u16x8*)&kp[(size_t)(s1 + r) * DHH + c];
                rv[m] = *(const u16x8*)&vp[(size_t)r * SS + s1 + c];
            }
        }
        f32x4 acc[4] = {};
#pragma unroll
        for (int ks = 0; ks < 64; ks += 32) {
            short8 bf = *(const short8*)&qt[tl][ks + quad * 8];
#pragma unroll
            for (int mt = 0; mt < 4; mt++) {
                short8 af = *(const short8*)&kt[mt * 16 + l16][ks + quad * 8];
                acc[mt] = MFMA16(af, bf, acc[mt]);
            }
        }
        // Praw -> pt[t][s], packed 4x ds_write_b64
#pragma unroll
        for (int mt = 0; mt < 4; mt++) {
            u16x4 pk;
#pragma unroll
            for (int reg = 0; reg < 4; reg++)
                pk[reg] = mkv ? f2bu(EXP2(acc[mt][reg])) : (u16)0;
            *(u16x4*)&pt[tl][mt * 16 + quad * 4] = pk;
        }
        __syncthreads();
#pragma unroll
        for (int ks = 0; ks < 64; ks += 32) {
            short8 bf = *(const short8*)&pt[tl][ks + quad * 8];
#pragma unroll
            for (int mt = 0; mt < 4; mt++) {
                short8 af = *(const short8*)&vt[mt * 16 + l16][ks + quad * 8];
                oacc[mt] = MFMA16(af, bf, oacc[mt]);
            }
        }
    }
    __syncthreads();
#pragma unroll
    for (int mt = 0; mt < 4; mt++) {
        u16x4 pk;
#pragma unroll
        for (int reg = 0; reg < 4; reg++) pk[reg] = f2bu(oacc[mt][reg]);
        *(u16x4*)&pt[tl][mt * 16 + quad * 4] = pk;
    }
    __syncthreads();
#pragma unroll
    for (int i = 0; i < 2; i++) {
        int id = tid * 2 + i;
        int r = id >> 3, c = (id & 7) * 8;
        *(u16x8*)&aT[((size_t)b * TT + t0 + r) * EE + h * 64 + c] =
            *(const u16x8*)&pt[r][c];
    }
}

// ---------------------------------------------------------------------------
extern "C" void kernel_launch(void* const* d_in, const int* in_sizes, int n_in,
                              void* d_out, int out_size, void* d_ws, size_t ws_size,
                              hipStream_t stream) {
    const float* x        = (const float*)d_in[0];
    const float* ctx      = (const float*)d_in[1];
    const int*   mask     = (const int*)d_in[2];
    const int*   mask_ctx = (const int*)d_in[3];
    const float* qw  = (const float*)d_in[4];
    const float* qbi = (const float*)d_in[5];
    const float* kw  = (const float*)d_in[6];
    const float* kbi = (const float*)d_in[7];
    const float* vw  = (const float*)d_in[8];
    const float* vbi = (const float*)d_in[9];
    const float* ow  = (const float*)d_in[10];
    const float* obi = (const float*)d_in[11];
    const float* gq = (const float*)d_in[12];
    const float* bq = (const float*)d_in[13];
    const float* gk = (const float*)d_in[14];
    const float* bk = (const float*)d_in[15];
    const float* gv = (const float*)d_in[16];
    const float* bv = (const float*)d_in[17];

    // workspace carve (~54 MB)
    u16* p = (u16*)d_ws;
    u16* wqn = p; p += (size_t)EE * EE;
    u16* wkn = p; p += (size_t)EE * CCH;
    u16* wvn = p; p += (size_t)EE * CCH;
    u16* won = p; p += (size_t)EE * EE;
    u16* xT  = p; p += (size_t)NB * TT * EE;        // [b][t][e]
    u16* cT  = p; p += (size_t)NB * SS * CCH;       // [b][s][c]
    u16* yv  = p; p += (size_t)NB * EE * SS;        // v proj out, LN+scale in place
    u16* qT  = p; p += (size_t)NB * NH * TT * DHH;  // [bh][t][d], pre-scaled
    u16* kT  = p; p += (size_t)NB * NH * SS * DHH;  // [bh][s][d]
    u16* aT  = p; p += (size_t)NB * TT * EE;        // attn out [b][t][e]

    // 1) weight standardization (all 4 in one dispatch)
    ws_norm4<<<dim3(1024, 4), 256, 0, stream>>>(qw, kw, vw, ow, wqn, wkn, wvn, won);

    // 2) fused transpose of x and ctx to [l][i] bf16
    transpose2_f2b<<<dim3(16, 28, NB), 256, 0, stream>>>(x, ctx, xT, cT);

    // 3) fused q/k/v projections + per-head LN epilogue (q,k) -> qT/kT; v -> yv
    proj_qkv<<<dim3(16, 24, NB), 256, 0, stream>>>(
        wqn, wkn, wvn, xT, cT, qbi, kbi, vbi, mask, mask_ctx,
        gq, bq, gk, bk, qT, kT, yv);

    // 4) softmax denominators + fused V LN with mask_ctx/l fold (in place)
    attn_stats_mfma<<<dim3(SS / 64, NH, NB), 256, 0, stream>>>(
        qT, kT, mask, mask_ctx, gv, bv, yv);

    // 5) PV pass -> aT [b][t][e] directly
    attn_pv_mfma<<<dim3(TT / 64, NH, NB), 256, 0, stream>>>(qT, kT, yv, mask, aT);

    // 6) o-proj (+mask +f32 residual) -> f32 d_out
    proj_o<<<dim3(16, 8, NB), 256, 0, stream>>>(won, aT, obi, mask, x, (float*)d_out);
}